// Round 5
// baseline (1553.394 us; speedup 1.0000x reference)
//
#include <hip/hip_runtime.h>
#include <hip/hip_bf16.h>
#include <stdint.h>

// ---------------- problem constants ----------------
#define DIMC 1024
#define HEADS 8
#define HDIM 128
#define FFND 4096
#define BATCH 32
#define SEQ 1024
#define SROWS (BATCH*SEQ)          // 32768
#define QSTR 3072                  // fused qkv row stride

typedef unsigned short u16;
typedef short short4v __attribute__((ext_vector_type(4)));
typedef short short8 __attribute__((ext_vector_type(8)));
typedef float f32x4 __attribute__((ext_vector_type(4)));
typedef float f32x16 __attribute__((ext_vector_type(16)));
typedef __bf16 bf16x8 __attribute__((ext_vector_type(8)));

// fp32 -> bf16 round-to-nearest-even
__device__ __forceinline__ u16 f2bf(float f) {
    union { float f; uint32_t u; } x{f};
    uint32_t r = x.u + 0x7FFFu + ((x.u >> 16) & 1u);
    return (u16)(r >> 16);
}
__device__ __forceinline__ float bf2f(u16 h) {
    union { uint32_t u; float f; } x;
    x.u = ((uint32_t)h) << 16;
    return x.f;
}

__device__ __forceinline__ f32x4 mfma16(short8 a, short8 b, f32x4 c) {
    return __builtin_amdgcn_mfma_f32_16x16x32_bf16(
        __builtin_bit_cast(bf16x8, a), __builtin_bit_cast(bf16x8, b), c, 0, 0, 0);
}
__device__ __forceinline__ f32x16 mfma32(short8 a, short8 b, f32x16 c) {
    return __builtin_amdgcn_mfma_f32_32x32x16_bf16(
        __builtin_bit_cast(bf16x8, a), __builtin_bit_cast(bf16x8, b), c, 0, 0, 0);
}

// async global->LDS, 16 bytes per lane; lds must be the wave-uniform base
__device__ __forceinline__ void gload_lds16(const u16* g, u16* lds) {
    __builtin_amdgcn_global_load_lds(
        (const __attribute__((address_space(1))) uint32_t*)g,
        (__attribute__((address_space(3))) uint32_t*)lds, 16, 0, 0);
}

// DPP rotate-add within 16-lane row (full 16-lane sum via 8,4,2,1)
#define DPP_RORADD(x, ctrl) do {                                               \
    int _t = __builtin_amdgcn_mov_dpp(__builtin_bit_cast(int, (x)), (ctrl),    \
                                      0xf, 0xf, true);                         \
    (x) += __builtin_bit_cast(float, _t); } while (0)

// P (normalized, f32, swapped-QK layout: q=l15, m=(lg,reg)) -> PV A-fragment
// (q=l15, k-elems m=8*lg..8*lg+7) purely in registers. p0 = m-subtile 0-15,
// p1 = m-subtile 16-31 of the 32-key chunk.
__device__ __forceinline__ short8 p2frag(f32x4 p0, f32x4 p1, int lane) {
    uint32_t a, b, c, d;
    asm("v_cvt_pk_bf16_f32 %0, %1, %2" : "=v"(a) : "v"(p0[0]), "v"(p0[1]));
    asm("v_cvt_pk_bf16_f32 %0, %1, %2" : "=v"(b) : "v"(p0[2]), "v"(p0[3]));
    asm("v_cvt_pk_bf16_f32 %0, %1, %2" : "=v"(c) : "v"(p1[0]), "v"(p1[1]));
    asm("v_cvt_pk_bf16_f32 %0, %1, %2" : "=v"(d) : "v"(p1[2]), "v"(p1[3]));
    uint32_t ax = (uint32_t)__shfl_xor((int)a, 32);
    uint32_t bx = (uint32_t)__shfl_xor((int)b, 32);
    uint32_t cx = (uint32_t)__shfl_xor((int)c, 32);
    uint32_t dx = (uint32_t)__shfl_xor((int)d, 32);
    const bool up = (lane & 32) != 0;
    uint32_t P = up ? cx : a, Q = up ? c : ax;
    uint32_t R = up ? dx : b, S = up ? d : bx;
    uint32_t Px = (uint32_t)__shfl_xor((int)P, 16);
    uint32_t Qx = (uint32_t)__shfl_xor((int)Q, 16);
    uint32_t Rx = (uint32_t)__shfl_xor((int)R, 16);
    uint32_t Sx = (uint32_t)__shfl_xor((int)S, 16);
    const bool odd = (lane & 16) != 0;
    uint32_t w0 = odd ? Qx : P,  w1 = odd ? Sx : R;
    uint32_t w2 = odd ? Q  : Px, w3 = odd ? S  : Rx;
    union { uint32_t w[4]; short8 s; } u;
    u.w[0] = w0; u.w[1] = w1; u.w[2] = w2; u.w[3] = w3;
    return u.s;
}

// ---------------- cast fp32 -> bf16 (vectorized) ----------------
__global__ __launch_bounds__(256) void k_cast(const float* __restrict__ in,
                                              u16* __restrict__ out, int n4) {
    int i = blockIdx.x * 256 + threadIdx.x;
    if (i < n4) {
        f32x4 v = ((const f32x4*)in)[i];
        uint32_t lo = f2bf(v[0]) | ((uint32_t)f2bf(v[1]) << 16);
        uint32_t hi = f2bf(v[2]) | ((uint32_t)f2bf(v[3]) << 16);
        ((uint2*)out)[i] = make_uint2(lo, hi);
    }
}

// ---------------- W (K x N fp32) -> Wt (N x K bf16), tiled ----------------
__global__ __launch_bounds__(256) void k_transpose_cast(const float* __restrict__ W,
                                                        u16* __restrict__ Wt,
                                                        int K, int N) {
    __shared__ u16 tile[32][33];
    int n0 = blockIdx.x * 32, k0 = blockIdx.y * 32;
    int tx = threadIdx.x, ty = threadIdx.y;   // 32 x 8
#pragma unroll
    for (int i = 0; i < 32; i += 8)
        tile[ty + i][tx] = f2bf(W[(size_t)(k0 + ty + i) * N + n0 + tx]);
    __syncthreads();
#pragma unroll
    for (int i = 0; i < 32; i += 8)
        Wt[(size_t)(n0 + ty + i) * K + k0 + tx] = tile[tx][ty + i];
}

// ---------------- GEMM 256x256, BK=32, 4-slot ring, counted vmcnt -------------
// R4: 32x32x16 MFMA (+15% FLOP/cyc vs 16x16x32, half the MFMA instructions,
// identical LDS traffic).  LDS chunks are [32 rows][16 k] fragment-linear.
// C/D layout (HW-verified m74/m101): col=lane&31, row=(r&3)+8*(r>>2)+4*(lane>>5).
template<bool OUT_BF16, bool RELU, bool BIAS, bool VSPLIT>
__global__ __launch_bounds__(512, 2) void k_gemm256(const u16* __restrict__ A,
                                                    const u16* __restrict__ Bt,
                                                    const float* __restrict__ bias,
                                                    void* __restrict__ C,
                                                    u16* __restrict__ Vt,
                                                    int M, int N, int K) {
    union Smem {
        struct { u16 A[4][8192]; u16 B[4][8192]; } k;   // 128KB ring
        u16 ob[64 * 264];                                // bf16 strip (33KB)
        float of[64 * 268];                              // fp32 strip (69KB)
        u16 vt[256 * 66];                                // transposed strip (33KB)
    };
    __shared__ Smem smem;
    const int tid = threadIdx.x;
    const int lane = tid & 63, wv = tid >> 6;
    const int wm = wv >> 2, wn = wv & 3;
    const int l31 = lane & 31, lg2 = lane >> 5;
    // XCD-aware bijective swizzle (requires nwg % 8 == 0 — all our grids comply)
    const int gx = gridDim.x;
    const int nwg = gx * gridDim.y;
    const int id = blockIdx.y * gx + blockIdx.x;
    const int id2 = (id & 7) * (nwg >> 3) + (id >> 3);
    const int row0 = (id2 / gx) << 8, col0 = (id2 % gx) << 8;
    const int NT = K >> 5;

    // chunk c (of 16): c>>1 = 32-row/col block, c&1 = k-half (16 wide)
#define STAGE_A(tt) {                                                          \
    int _t = (tt);                                                             \
    _Pragma("unroll")                                                          \
    for (int i = 0; i < 2; ++i) {                                              \
        int c = wv * 2 + i;                                                    \
        gload_lds16(A + (size_t)(row0 + (c >> 1) * 32 + l31) * K + _t * 32     \
                    + (c & 1) * 16 + lg2 * 8,                                  \
                    &smem.k.A[_t & 3][c * 512]);                               \
    } }
#define STAGE_B(tt) {                                                          \
    int _t = (tt);                                                             \
    _Pragma("unroll")                                                          \
    for (int i = 0; i < 2; ++i) {                                              \
        int c = wv * 2 + i;                                                    \
        gload_lds16(Bt + (size_t)(col0 + (c >> 1) * 32 + l31) * K + _t * 32    \
                    + (c & 1) * 16 + lg2 * 8,                                  \
                    &smem.k.B[_t & 3][c * 512]);                               \
    } }

    STAGE_A(0); STAGE_B(0);
    STAGE_A(1); STAGE_B(1);
    STAGE_A(2); STAGE_B(2);

    f32x16 acc[4][2] = {};
    for (int t = 0; t < NT; ++t) {
        const int slot = t & 3;
        if (t <= NT - 3)      asm volatile("s_waitcnt vmcnt(8)" ::: "memory");
        else if (t == NT - 2) asm volatile("s_waitcnt vmcnt(4)" ::: "memory");
        else                  asm volatile("s_waitcnt vmcnt(0)" ::: "memory");
        __builtin_amdgcn_s_barrier();
        __builtin_amdgcn_sched_barrier(0);

        // wave's chunks: A blocks wm*4..wm*4+3 -> chunks wm*8.. ; B blocks wn*2..+1
        const u16* Ab = &smem.k.A[slot][(wm * 8) * 512];
        const u16* Bb = &smem.k.B[slot][(wn * 4) * 512];

        if (t + 3 < NT) STAGE_A(t + 3);
        short8 bf[2], af[4];
        // k-half 0
#pragma unroll
        for (int bn = 0; bn < 2; ++bn) bf[bn] = *(const short8*)(Bb + (bn * 2) * 512 + lane * 8);
#pragma unroll
        for (int am = 0; am < 4; ++am) af[am] = *(const short8*)(Ab + (am * 2) * 512 + lane * 8);
        __builtin_amdgcn_s_setprio(1);
#pragma unroll
        for (int am = 0; am < 4; ++am)
#pragma unroll
            for (int bn = 0; bn < 2; ++bn)
                acc[am][bn] = mfma32(af[am], bf[bn], acc[am][bn]);
        __builtin_amdgcn_s_setprio(0);

        if (t + 3 < NT) STAGE_B(t + 3);
        // k-half 1
#pragma unroll
        for (int bn = 0; bn < 2; ++bn) bf[bn] = *(const short8*)(Bb + (bn * 2 + 1) * 512 + lane * 8);
#pragma unroll
        for (int am = 0; am < 4; ++am) af[am] = *(const short8*)(Ab + (am * 2 + 1) * 512 + lane * 8);
        __builtin_amdgcn_s_setprio(1);
#pragma unroll
        for (int am = 0; am < 4; ++am)
#pragma unroll
            for (int bn = 0; bn < 2; ++bn)
                acc[am][bn] = mfma32(af[am], bf[bn], acc[am][bn]);
        __builtin_amdgcn_s_setprio(0);
    }
#undef STAGE_A
#undef STAGE_B

    // -------- epilogue: 4 strips of 64 rows via LDS, coalesced vector stores ----
    const bool vpath = VSPLIT && (col0 >= 2048);
    __syncthreads();
#pragma unroll
    for (int s = 0; s < 4; ++s) {
        if (s) __syncthreads();
        if (wm == (s >> 1)) {
            const int am0 = (s & 1) * 2;
#pragma unroll
            for (int am2 = 0; am2 < 2; ++am2)
#pragma unroll
                for (int bn = 0; bn < 2; ++bn) {
                    int c = wn * 64 + bn * 32 + l31;
                    float bv = BIAS ? bias[col0 + c] : 0.f;
#pragma unroll
                    for (int r = 0; r < 16; ++r) {
                        int lr = am0 * 0 + am2 * 32 + (r & 3) + 8 * (r >> 2) + 4 * lg2;
                        float v = acc[am0 + am2][bn][r] + bv;
                        if (RELU) v = fmaxf(v, 0.f);
                        if (vpath)         smem.vt[c * 66 + lr] = f2bf(v);
                        else if (OUT_BF16) smem.ob[lr * 264 + c] = f2bf(v);
                        else               smem.of[lr * 268 + c] = v;
                    }
                }
        }
        __syncthreads();
        const int gr0 = row0 + s * 64;
        if (vpath) {
            const int bb = gr0 >> 10;        // batch (256-row tiles never cross)
            const int mb = gr0 & 1023;       // m base within sequence
#pragma unroll
            for (int it = 0; it < 4; ++it) {
                int idx = it * 512 + tid;    // 2048 segs: dc in [0,256), mseg in [0,8)
                int dc = idx >> 3, mseg = idx & 7;
                int hh = (col0 - 2048 + dc) >> 7;
                int dd = (col0 - 2048 + dc) & 127;
                *(short8*)(Vt + ((size_t)(bb * 8 + hh)) * (HDIM * SEQ)
                              + (size_t)dd * SEQ + mb + mseg * 8) =
                    *(const short8*)(&smem.vt[dc * 66 + mseg * 8]);
            }
        } else if (OUT_BF16) {
#pragma unroll
            for (int it = 0; it < 4; ++it) {
                int idx = it * 512 + tid;          // 2048 segs of 8 u16
                int r = idx >> 5, seg = idx & 31;
                *(short8*)((u16*)C + (size_t)(gr0 + r) * N + col0 + seg * 8) =
                    *(const short8*)(&smem.ob[r * 264 + seg * 8]);
            }
        } else {
#pragma unroll
            for (int it = 0; it < 8; ++it) {
                int idx = it * 512 + tid;          // 4096 segs of 4 f32
                int r = idx >> 6, seg = idx & 63;
                *(f32x4*)((float*)C + (size_t)(gr0 + r) * N + col0 + seg * 4) =
                    *(const f32x4*)(&smem.of[r * 268 + seg * 4]);
            }
        }
    }
}

// ---------------- attention: 4 waves x 32 q-rows, swapped-QK, in-register P ---
__global__ __launch_bounds__(256, 3) void k_attn(const u16* __restrict__ QKV,
                                                 const u16* __restrict__ Vt,
                                                 u16* __restrict__ O,
                                                 float* __restrict__ csp) {
    union Sm {
        u16 K2[3][8192];                                   // pass A: 64-key ring-3 (48KB)
        struct { u16 Kl[3][4096]; u16 Vl[3][4096]; } pb;   // pass B: 32-key ring-3
    };
    __shared__ Sm sm;
    __shared__ float cs[1024];       // column sums (4KB)
    const int id = blockIdx.x;
    const int id2 = (id & 7) * 256 + (id >> 3);   // bijective, 2048 = 8*256
    const int qt = id2 & 7, bh = id2 >> 3;
    const int b = bh >> 3, h = bh & 7;
    const int tid = threadIdx.x, lane = tid & 63, wv = tid >> 6;  // wv in [0,4)
    const int l15 = lane & 15, lg = lane >> 4;

    for (int i = tid; i < 1024; i += 256) cs[i] = 0.f;

    const int q0 = qt * 128 + wv * 32;           // this wave's 32 q-rows
    const u16* qbaseA = QKV + (size_t)(b * SEQ + q0 + l15) * QSTR + h * HDIM + lg * 8;
    const u16* qbaseB = qbaseA + (size_t)16 * QSTR;
    short8 qfA[4], qfB[4];
#pragma unroll
    for (int kk = 0; kk < 4; ++kk) {
        qfA[kk] = *(const short8*)(qbaseA + kk * 32);
        qfB[kk] = *(const short8*)(qbaseB + kk * 32);
    }
    // drain Q loads so counted vmcnt below only tracks stage loads
    asm volatile("s_waitcnt vmcnt(0)" ::: "memory");
    const float CEXP = 0.12751743f;   // (1/sqrt(128)) * log2(e)
    const u16* kbase = QKV + (size_t)(b * SEQ) * QSTR + 1024 + h * HDIM;
    const u16* vtb = Vt + (size_t)bh * HDIM * SEQ;

#define STAGE_K2(tt, sl) { _Pragma("unroll")                                    \
    for (int i = 0; i < 4; ++i) {                                               \
        gload_lds16(kbase + (size_t)((tt) * 64 + wv * 16 + l15) * QSTR          \
                    + i * 32 + lg * 8, &sm.K2[sl][(wv * 4 + i) * 512]); } }
#define STAGE_K(tt, sl) { _Pragma("unroll")                                     \
    for (int i = 0; i < 2; ++i) { int c = wv * 2 + i;                           \
        gload_lds16(kbase + (size_t)((tt) * 32 + (c >> 2) * 16 + l15) * QSTR    \
                    + (c & 3) * 32 + lg * 8, &sm.pb.Kl[sl][c * 512]); } }
#define STAGE_V(tt, sl) { _Pragma("unroll")                                     \
    for (int i = 0; i < 2; ++i) { int c = wv * 2 + i;                           \
        gload_lds16(vtb + (size_t)(c * 16 + l15) * SEQ + (tt) * 32 + lg * 8,    \
                    &sm.pb.Vl[sl][c * 512]); } }

    // ---------------- pass A: per-q rowsums of exp2(s*C), 64-key tiles ---------
    STAGE_K2(0, 0); STAGE_K2(1, 1);
    f32x4 rsA4 = {0.f, 0.f, 0.f, 0.f}, rsB4 = {0.f, 0.f, 0.f, 0.f};
    for (int t = 0; t < 16; ++t) {
        if (t < 15) asm volatile("s_waitcnt vmcnt(4)" ::: "memory");
        else        asm volatile("s_waitcnt vmcnt(0)" ::: "memory");
        __builtin_amdgcn_s_barrier();
        __builtin_amdgcn_sched_barrier(0);
        if (t < 14) STAGE_K2(t + 2, (t + 2) % 3);
        const u16* Kp = &sm.K2[t % 3][0];
        __builtin_amdgcn_s_setprio(1);
#pragma unroll
        for (int j = 0; j < 4; j += 2) {
            f32x4 s0 = {0.f,0.f,0.f,0.f}, s1 = {0.f,0.f,0.f,0.f};
            f32x4 s2 = {0.f,0.f,0.f,0.f}, s3 = {0.f,0.f,0.f,0.f};
#pragma unroll
            for (int kk = 0; kk < 4; ++kk) {
                short8 k0 = *(const short8*)(Kp + (j * 4 + kk) * 512 + lane * 8);
                short8 k1 = *(const short8*)(Kp + ((j + 1) * 4 + kk) * 512 + lane * 8);
                s0 = mfma16(k0, qfA[kk], s0);
                s1 = mfma16(k0, qfB[kk], s1);
                s2 = mfma16(k1, qfA[kk], s2);
                s3 = mfma16(k1, qfB[kk], s3);
            }
#pragma unroll
            for (int r = 0; r < 4; ++r) {
                rsA4[r] += __builtin_amdgcn_exp2f(s0[r] * CEXP)
                         + __builtin_amdgcn_exp2f(s2[r] * CEXP);
                rsB4[r] += __builtin_amdgcn_exp2f(s1[r] * CEXP)
                         + __builtin_amdgcn_exp2f(s3[r] * CEXP);
            }
        }
        __builtin_amdgcn_s_setprio(0);
    }
    float rsA = (rsA4[0] + rsA4[1]) + (rsA4[2] + rsA4[3]);
    float rsB = (rsB4[0] + rsB4[1]) + (rsB4[2] + rsB4[3]);
    rsA += __shfl_xor(rsA, 16); rsA += __shfl_xor(rsA, 32);
    rsB += __shfl_xor(rsB, 16); rsB += __shfl_xor(rsB, 32);
    const float invA = 1.f / rsA, invB = 1.f / rsB;

    // ---------------- pass B: P = exp/rowsum ; O += P V ; column sums ----------
    __builtin_amdgcn_s_barrier();
    STAGE_K(0, 0); STAGE_V(0, 0);
    STAGE_K(1, 1); STAGE_V(1, 1);
    f32x4 odA[8] = {}, odB[8] = {};
    for (int t = 0; t < 32; ++t) {
        const int m0 = t * 32;
        if (t < 31) asm volatile("s_waitcnt vmcnt(4)" ::: "memory");
        else        asm volatile("s_waitcnt vmcnt(0)" ::: "memory");
        __builtin_amdgcn_s_barrier();
        __builtin_amdgcn_sched_barrier(0);
        if (t < 30) { STAGE_K(t + 2, (t + 2) % 3); STAGE_V(t + 2, (t + 2) % 3); }
        const u16* Kp = &sm.pb.Kl[t % 3][0];
        f32x4 sA0 = {0.f,0.f,0.f,0.f}, sA1 = {0.f,0.f,0.f,0.f};
        f32x4 sB0 = {0.f,0.f,0.f,0.f}, sB1 = {0.f,0.f,0.f,0.f};
        __builtin_amdgcn_s_setprio(1);
#pragma unroll
        for (int kk = 0; kk < 4; ++kk) {
            short8 k0 = *(const short8*)(Kp + kk * 512 + lane * 8);
            short8 k1 = *(const short8*)(Kp + (4 + kk) * 512 + lane * 8);
            sA0 = mfma16(k0, qfA[kk], sA0);
            sA1 = mfma16(k1, qfA[kk], sA1);
            sB0 = mfma16(k0, qfB[kk], sB0);
            sB1 = mfma16(k1, qfB[kk], sB1);
        }
        __builtin_amdgcn_s_setprio(0);
        f32x4 pA0, pA1, pB0, pB1;
#pragma unroll
        for (int r = 0; r < 4; ++r) {
            pA0[r] = __builtin_amdgcn_exp2f(sA0[r] * CEXP) * invA;
            pA1[r] = __builtin_amdgcn_exp2f(sA1[r] * CEXP) * invA;
            pB0[r] = __builtin_amdgcn_exp2f(sB0[r] * CEXP) * invB;
            pB1[r] = __builtin_amdgcn_exp2f(sB1[r] * CEXP) * invB;
        }
        float csv[8];
#pragma unroll
        for (int r = 0; r < 4; ++r) {
            csv[r]     = pA0[r] + pB0[r];
            csv[4 + r] = pA1[r] + pB1[r];
        }
#pragma unroll
        for (int j2 = 0; j2 < 8; ++j2) {
            DPP_RORADD(csv[j2], 0x128);
            DPP_RORADD(csv[j2], 0x124);
            DPP_RORADD(csv[j2], 0x122);
            DPP_RORADD(csv[j2], 0x121);
        }
        float cval = csv[0];
        cval = (l15 == 1) ? csv[1] : cval;
        cval = (l15 == 2) ? csv[2] : cval;
        cval = (l15 == 3) ? csv[3] : cval;
        cval = (l15 == 4) ? csv[4] : cval;
        cval = (l15 == 5) ? csv[5] : cval;
        cval = (l15 == 6) ? csv[6] : cval;
        cval = (l15 == 7) ? csv[7] : cval;
        if (l15 < 8) {
            int mw = (l15 < 4) ? (lg * 4 + l15) : (16 + lg * 4 + (l15 - 4));
            atomicAdd(&cs[m0 + mw], cval);
        }
        short8 paA = p2frag(pA0, pA1, lane);
        short8 paB = p2frag(pB0, pB1, lane);
        const u16* Vb_ = &sm.pb.Vl[t % 3][0];
        __builtin_amdgcn_s_setprio(1);
#pragma unroll
        for (int db = 0; db < 8; ++db) {
            short8 vf = *(const short8*)(Vb_ + db * 512 + lane * 8);
            odA[db] = mfma16(paA, vf, odA[db]);
            odB[db] = mfma16(paB, vf, odB[db]);
        }
        __builtin_amdgcn_s_setprio(0);
    }
#undef STAGE_K2
#undef STAGE_K
#undef STAGE_V
    __syncthreads();   // make all waves' cs atomics visible before drain
    u16* obA = O + (size_t)(b * SEQ + q0 + lg * 4) * DIMC + h * HDIM + l15;
    u16* obB = obA + (size_t)16 * DIMC;
#pragma unroll
    for (int db = 0; db < 8; ++db)
#pragma unroll
        for (int r = 0; r < 4; ++r) {
            obA[(size_t)r * DIMC + db * 16] = f2bf(odA[db][r]);
            obB[(size_t)r * DIMC + db * 16] = f2bf(odB[db][r]);
        }
    for (int m = tid; m < 1024; m += 256)
        csp[((size_t)bh * 8 + qt) * 1024 + m] = cs[m];
}

// ---------------- LN1: LN(x_f32 + proj_bf16) -> bf16 out ----------------
__global__ __launch_bounds__(256) void k_ln1(const float* __restrict__ xa,
                                             const u16* __restrict__ pj,
                                             const float* __restrict__ g,
                                             const float* __restrict__ bt,
                                             u16* __restrict__ ob) {
    const int row = blockIdx.x;
    const int t = threadIdx.x, lane = t & 63, wv = t >> 6;
    f32x4 va = ((const f32x4*)(xa + (size_t)row * DIMC))[t];
    short4v hv = ((const short4v*)(pj + (size_t)row * DIMC))[t];
    f32x4 s;
#pragma unroll
    for (int j = 0; j < 4; ++j) s[j] = va[j] + bf2f((u16)hv[j]);
    float sum = s[0] + s[1] + s[2] + s[3];
    float sq = s[0]*s[0] + s[1]*s[1] + s[2]*s[2] + s[3]*s[3];
#pragma unroll
    for (int o = 1; o < 64; o <<= 1) { sum += __shfl_xor(sum, o); sq += __shfl_xor(sq, o); }
    __shared__ float red[8];
    if (lane == 0) { red[wv] = sum; red[4 + wv] = sq; }
    __syncthreads();
    sum = red[0] + red[1] + red[2] + red[3];
    sq  = red[4] + red[5] + red[6] + red[7];
    float mu = sum * (1.f / DIMC);
    float rstd = rsqrtf(sq * (1.f / DIMC) - mu * mu + 1e-5f);
    f32x4 gg = ((const f32x4*)g)[t];
    f32x4 bb = ((const f32x4*)bt)[t];
    uint32_t lo, hi;
    float o0 = (s[0] - mu) * rstd * gg[0] + bb[0];
    float o1 = (s[1] - mu) * rstd * gg[1] + bb[1];
    float o2 = (s[2] - mu) * rstd * gg[2] + bb[2];
    float o3 = (s[3] - mu) * rstd * gg[3] + bb[3];
    lo = f2bf(o0) | ((uint32_t)f2bf(o1) << 16);
    hi = f2bf(o2) | ((uint32_t)f2bf(o3) << 16);
    ((uint2*)(ob + (size_t)row * DIMC))[t] = make_uint2(lo, hi);
}

// ---------------- LN2: LN(h_bf16 + ff2_f32) -> fp32, in-place over ff2 --------
__global__ __launch_bounds__(256) void k_ln2(const u16* __restrict__ xa,
                                             const float* __restrict__ g,
                                             const float* __restrict__ bt,
                                             float* __restrict__ of) {
    const int row = blockIdx.x;
    const int t = threadIdx.x, lane = t & 63, wv = t >> 6;
    short4v hv = ((const short4v*)(xa + (size_t)row * DIMC))[t];
    f32x4 fv = ((const f32x4*)(of + (size_t)row * DIMC))[t];
    f32x4 s;
#pragma unroll
    for (int j = 0; j < 4; ++j) s[j] = bf2f((u16)hv[j]) + fv[j];
    float sum = s[0] + s[1] + s[2] + s[3];
    float sq = s[0]*s[0] + s[1]*s[1] + s[2]*s[2] + s[3]*s[3];
#pragma unroll
    for (int o = 1; o < 64; o <<= 1) { sum += __shfl_xor(sum, o); sq += __shfl_xor(sq, o); }
    __shared__ float red[8];
    if (lane == 0) { red[wv] = sum; red[4 + wv] = sq; }
    __syncthreads();
    sum = red[0] + red[1] + red[2] + red[3];
    sq  = red[4] + red[5] + red[6] + red[7];
    float mu = sum * (1.f / DIMC);
    float rstd = rsqrtf(sq * (1.f / DIMC) - mu * mu + 1e-5f);
    f32x4 gg = ((const f32x4*)g)[t];
    f32x4 bb = ((const f32x4*)bt)[t];
    f32x4 o4;
#pragma unroll
    for (int j = 0; j < 4; ++j) o4[j] = (s[j] - mu) * rstd * gg[j] + bb[j];
    ((f32x4*)(of + (size_t)row * DIMC))[t] = o4;
}

// ---------------- halting: reduce column-sum partials, /H, softmax, add --------
__global__ __launch_bounds__(256) void k_halt(const float* __restrict__ csp,
                                              const float* __restrict__ hs,
                                              float* __restrict__ halt_out,
                                              float* __restrict__ a_out) {
    const int b = blockIdx.x, t = threadIdx.x, lane = t & 63, wv = t >> 6;
    const float* base = csp + (size_t)b * 65536;   // 8 h * 8 qt * 1024
    float acc[4] = {0.f, 0.f, 0.f, 0.f};
    for (int s2 = 0; s2 < 64; ++s2) {
#pragma unroll
        for (int j = 0; j < 4; ++j) acc[j] += base[(size_t)s2 * 1024 + j * 256 + t];
    }
    float mx = -1e30f;
#pragma unroll
    for (int j = 0; j < 4; ++j) { acc[j] *= 0.125f; mx = fmaxf(mx, acc[j]); }
#pragma unroll
    for (int o = 1; o < 64; o <<= 1) mx = fmaxf(mx, __shfl_xor(mx, o));
    __shared__ float red[8];
    if (lane == 0) red[wv] = mx;
    __syncthreads();
    mx = fmaxf(fmaxf(red[0], red[1]), fmaxf(red[2], red[3]));
    float e[4]; float sum = 0.f;
#pragma unroll
    for (int j = 0; j < 4; ++j) { e[j] = __expf(acc[j] - mx); sum += e[j]; }
#pragma unroll
    for (int o = 1; o < 64; o <<= 1) sum += __shfl_xor(sum, o);
    if (lane == 0) red[4 + wv] = sum;
    __syncthreads();
    sum = red[4] + red[5] + red[6] + red[7];
    float inv = 1.f / sum;
#pragma unroll
    for (int j = 0; j < 4; ++j) {
        int m = j * 256 + t;
        float a = e[j] * inv;
        a_out[b * SEQ + m] = a;
        halt_out[b * SEQ + m] = hs[b * SEQ + m] + a;
    }
}

// =======================================================================
// workspace layout (<= 352 MiB):
//   [0,64)    xb -> o_b -> hb
//   [64,256)  qkv bf16 (192MB; V-third never written) -> proj bf16 [64,128)
//   [64,320)  ff1 bf16 full (256MB, over qkv+Vt; both dead after LN1/attn)
//   [256,320) Vt (written by QKV gemm epilogue, dead after attn)
//   [320,344) transposed bf16 weights (WqkvT 6MB | WpT 2MB | W1T 8MB | W2T 8MB)
//   [344,352) colsum partials
//   ff2 fp32 goes straight into d_out; LN2 runs in-place.
// =======================================================================
extern "C" void kernel_launch(void* const* d_in, const int* in_sizes, int n_in,
                              void* d_out, int out_size, void* d_ws, size_t ws_size,
                              hipStream_t stream) {
    (void)in_sizes; (void)n_in; (void)out_size; (void)ws_size;
    const float* x   = (const float*)d_in[0];
    const float* hs  = (const float*)d_in[1];
    const float* Wq  = (const float*)d_in[2];
    const float* Wkv = (const float*)d_in[3];
    const float* Wp  = (const float*)d_in[4];
    const float* bp  = (const float*)d_in[5];
    const float* W1  = (const float*)d_in[6];
    const float* b1  = (const float*)d_in[7];
    const float* W2  = (const float*)d_in[8];
    const float* b2  = (const float*)d_in[9];
    const float* g1  = (const float*)d_in[10];
    const float* be1 = (const float*)d_in[11];
    const float* g2  = (const float*)d_in[12];
    const float* be2 = (const float*)d_in[13];

    float* out = (float*)d_out;
    float* halt_out = out + (size_t)SROWS * DIMC;
    float* a_out = halt_out + SROWS;

    char* w = (char*)d_ws;
    const size_t MB = 1024 * 1024;
    u16*  xb    = (u16*)(w);
    u16*  qkv   = (u16*)(w + 64 * MB);
    u16*  Vt    = (u16*)(w + 256 * MB);
    u16*  WqkvT = (u16*)(w + 320 * MB);
    u16*  WpT   = (u16*)(w + 326 * MB);
    u16*  W1T   = (u16*)(w + 328 * MB);
    u16*  W2T   = (u16*)(w + 336 * MB);
    float* csp  = (float*)(w + 344 * MB);
    u16*  o_b   = (u16*)(w);                // reuse xb (dead after QKV gemm)
    u16*  projb = (u16*)(w + 64 * MB);      // bf16, over qkv Q-third (dead after attn)
    u16*  hb    = (u16*)(w);                // reuse o_b (dead after proj)
    u16*  ff1   = (u16*)(w + 64 * MB);      // full 256MB span [64,320)

    dim3 tb(32, 8);
    // casts + weight transposes (Wq and Wkv land in one contiguous WqkvT)
    k_cast<<<SROWS * DIMC / 4 / 256, 256, 0, stream>>>(x, xb, SROWS * DIMC / 4);
    k_transpose_cast<<<dim3(DIMC / 32, DIMC / 32), tb, 0, stream>>>(Wq, WqkvT, DIMC, DIMC);
    k_transpose_cast<<<dim3(2 * DIMC / 32, DIMC / 32), tb, 0, stream>>>(
        Wkv, WqkvT + (size_t)DIMC * DIMC, DIMC, 2 * DIMC);
    k_transpose_cast<<<dim3(DIMC / 32, DIMC / 32), tb, 0, stream>>>(Wp, WpT, DIMC, DIMC);
    k_transpose_cast<<<dim3(FFND / 32, DIMC / 32), tb, 0, stream>>>(W1, W1T, DIMC, FFND);
    k_transpose_cast<<<dim3(DIMC / 32, FFND / 32), tb, 0, stream>>>(W2, W2T, FFND, DIMC);
    // fused QKV gemm (N = 3072); V columns written transposed into Vt
    k_gemm256<true, false, false, true><<<dim3(QSTR / 256, SROWS / 256), 512, 0, stream>>>(
        xb, WqkvT, nullptr, qkv, Vt, SROWS, QSTR, DIMC);
    // attention (256 threads: 4 waves x 32 q-rows)
    k_attn<<<2048, 256, 0, stream>>>(qkv, Vt, o_b, csp);
    // output projection (+bp) -> bf16
    k_gemm256<true, false, true, false><<<dim3(DIMC / 256, SROWS / 256), 512, 0, stream>>>(
        o_b, WpT, bp, projb, nullptr, SROWS, DIMC, DIMC);
    // LN1: h = LN(x + proj) -> bf16 hb
    k_ln1<<<SROWS, 256, 0, stream>>>(x, projb, g1, be1, hb);
    // FFN, full-size single dispatches (FFN2 at 512 blocks = 2 blk/CU)
    k_gemm256<true, true, true, false><<<dim3(FFND / 256, SROWS / 256), 512, 0, stream>>>(
        hb, W1T, b1, ff1, nullptr, SROWS, FFND, DIMC);
    k_gemm256<false, false, true, false><<<dim3(DIMC / 256, SROWS / 256), 512, 0, stream>>>(
        ff1, W2T, b2, out, nullptr, SROWS, DIMC, FFND);
    // LN2 in-place over fp32 ff2 (= out)
    k_ln2<<<SROWS, 256, 0, stream>>>(hb, g2, be2, out);
    // halting score
    k_halt<<<BATCH, 256, 0, stream>>>(csp, hs, halt_out, a_out);
}

// Round 6
// 1441.816 us; speedup vs baseline: 1.0774x; 1.0774x over previous
//
#include <hip/hip_runtime.h>
#include <hip/hip_bf16.h>
#include <stdint.h>

// ---------------- problem constants ----------------
#define DIMC 1024
#define HEADS 8
#define HDIM 128
#define FFND 4096
#define BATCH 32
#define SEQ 1024
#define SROWS (BATCH*SEQ)          // 32768
#define QSTR 3072                  // fused qkv row stride

typedef unsigned short u16;
typedef short short4v __attribute__((ext_vector_type(4)));
typedef short short8 __attribute__((ext_vector_type(8)));
typedef float f32x4 __attribute__((ext_vector_type(4)));
typedef __bf16 bf16x8 __attribute__((ext_vector_type(8)));

// fp32 -> bf16 round-to-nearest-even
__device__ __forceinline__ u16 f2bf(float f) {
    union { float f; uint32_t u; } x{f};
    uint32_t r = x.u + 0x7FFFu + ((x.u >> 16) & 1u);
    return (u16)(r >> 16);
}
__device__ __forceinline__ float bf2f(u16 h) {
    union { uint32_t u; float f; } x;
    x.u = ((uint32_t)h) << 16;
    return x.f;
}

__device__ __forceinline__ f32x4 mfma16(short8 a, short8 b, f32x4 c) {
    return __builtin_amdgcn_mfma_f32_16x16x32_bf16(
        __builtin_bit_cast(bf16x8, a), __builtin_bit_cast(bf16x8, b), c, 0, 0, 0);
}

// async global->LDS, 16 bytes per lane; lds must be the wave-uniform base
__device__ __forceinline__ void gload_lds16(const u16* g, u16* lds) {
    __builtin_amdgcn_global_load_lds(
        (const __attribute__((address_space(1))) uint32_t*)g,
        (__attribute__((address_space(3))) uint32_t*)lds, 16, 0, 0);
}

// DPP rotate-add within 16-lane row (full 16-lane sum via 8,4,2,1)
#define DPP_RORADD(x, ctrl) do {                                               \
    int _t = __builtin_amdgcn_mov_dpp(__builtin_bit_cast(int, (x)), (ctrl),    \
                                      0xf, 0xf, true);                         \
    (x) += __builtin_bit_cast(float, _t); } while (0)

// P (normalized, f32, swapped-QK layout: q=l15, m=(lg,reg)) -> PV A-fragment
// (q=l15, k-elems m=8*lg..8*lg+7) purely in registers. p0 = m-subtile 0-15,
// p1 = m-subtile 16-31 of the 32-key chunk.
__device__ __forceinline__ short8 p2frag(f32x4 p0, f32x4 p1, int lane) {
    uint32_t a, b, c, d;
    asm("v_cvt_pk_bf16_f32 %0, %1, %2" : "=v"(a) : "v"(p0[0]), "v"(p0[1]));
    asm("v_cvt_pk_bf16_f32 %0, %1, %2" : "=v"(b) : "v"(p0[2]), "v"(p0[3]));
    asm("v_cvt_pk_bf16_f32 %0, %1, %2" : "=v"(c) : "v"(p1[0]), "v"(p1[1]));
    asm("v_cvt_pk_bf16_f32 %0, %1, %2" : "=v"(d) : "v"(p1[2]), "v"(p1[3]));
    uint32_t ax = (uint32_t)__shfl_xor((int)a, 32);
    uint32_t bx = (uint32_t)__shfl_xor((int)b, 32);
    uint32_t cx = (uint32_t)__shfl_xor((int)c, 32);
    uint32_t dx = (uint32_t)__shfl_xor((int)d, 32);
    const bool up = (lane & 32) != 0;
    uint32_t P = up ? cx : a, Q = up ? c : ax;
    uint32_t R = up ? dx : b, S = up ? d : bx;
    uint32_t Px = (uint32_t)__shfl_xor((int)P, 16);
    uint32_t Qx = (uint32_t)__shfl_xor((int)Q, 16);
    uint32_t Rx = (uint32_t)__shfl_xor((int)R, 16);
    uint32_t Sx = (uint32_t)__shfl_xor((int)S, 16);
    const bool odd = (lane & 16) != 0;
    uint32_t w0 = odd ? Qx : P,  w1 = odd ? Sx : R;
    uint32_t w2 = odd ? Q  : Px, w3 = odd ? S  : Rx;
    union { uint32_t w[4]; short8 s; } u;
    u.w[0] = w0; u.w[1] = w1; u.w[2] = w2; u.w[3] = w3;
    return u.s;
}

// ---------------- cast fp32 -> bf16 (vectorized) ----------------
__global__ __launch_bounds__(256) void k_cast(const float* __restrict__ in,
                                              u16* __restrict__ out, int n4) {
    int i = blockIdx.x * 256 + threadIdx.x;
    if (i < n4) {
        f32x4 v = ((const f32x4*)in)[i];
        uint32_t lo = f2bf(v[0]) | ((uint32_t)f2bf(v[1]) << 16);
        uint32_t hi = f2bf(v[2]) | ((uint32_t)f2bf(v[3]) << 16);
        ((uint2*)out)[i] = make_uint2(lo, hi);
    }
}

// ---------------- W (K x N fp32) -> Wt (N x K bf16), tiled ----------------
__global__ __launch_bounds__(256) void k_transpose_cast(const float* __restrict__ W,
                                                        u16* __restrict__ Wt,
                                                        int K, int N) {
    __shared__ u16 tile[32][33];
    int n0 = blockIdx.x * 32, k0 = blockIdx.y * 32;
    int tx = threadIdx.x, ty = threadIdx.y;   // 32 x 8
#pragma unroll
    for (int i = 0; i < 32; i += 8)
        tile[ty + i][tx] = f2bf(W[(size_t)(k0 + ty + i) * N + n0 + tx]);
    __syncthreads();
#pragma unroll
    for (int i = 0; i < 32; i += 8)
        Wt[(size_t)(n0 + ty + i) * K + k0 + tx] = tile[tx][ty + i];
}

// ---------------- GEMM 256x256, BK=32, 4-slot ring, counted vmcnt -------------
template<bool OUT_BF16, bool RELU, bool BIAS, bool VSPLIT>
__global__ __launch_bounds__(512, 2) void k_gemm256(const u16* __restrict__ A,
                                                    const u16* __restrict__ Bt,
                                                    const float* __restrict__ bias,
                                                    void* __restrict__ C,
                                                    u16* __restrict__ Vt,
                                                    int M, int N, int K) {
    union Smem {
        struct { u16 A[4][8192]; u16 B[4][8192]; } k;   // 128KB ring
        u16 ob[64 * 264];                                // bf16 strip (33KB)
        float of[64 * 268];                              // fp32 strip (69KB)
        u16 vt[256 * 66];                                // transposed strip (33KB)
    };
    __shared__ Smem smem;
    const int tid = threadIdx.x;
    const int lane = tid & 63, wv = tid >> 6;
    const int wm = wv >> 2, wn = wv & 3;
    const int l15 = lane & 15, lg = lane >> 4;
    // XCD-aware bijective swizzle (requires nwg % 8 == 0 — all our grids comply)
    const int gx = gridDim.x;
    const int nwg = gx * gridDim.y;
    const int id = blockIdx.y * gx + blockIdx.x;
    const int id2 = (id & 7) * (nwg >> 3) + (id >> 3);
    const int row0 = (id2 / gx) << 8, col0 = (id2 % gx) << 8;
    const int NT = K >> 5;

#define STAGE_A(tt) {                                                          \
    int _t = (tt);                                                             \
    _Pragma("unroll")                                                          \
    for (int i = 0; i < 2; ++i) {                                              \
        int blk = wv * 2 + i;                                                  \
        gload_lds16(A + (size_t)(row0 + blk * 16 + l15) * K + _t * 32 + lg * 8,\
                    &smem.k.A[_t & 3][blk * 512]);                             \
    } }
#define STAGE_B(tt) {                                                          \
    int _t = (tt);                                                             \
    _Pragma("unroll")                                                          \
    for (int i = 0; i < 2; ++i) {                                              \
        int blk = wv * 2 + i;                                                  \
        gload_lds16(Bt + (size_t)(col0 + blk * 16 + l15) * K + _t * 32 + lg * 8,\
                    &smem.k.B[_t & 3][blk * 512]);                             \
    } }

    STAGE_A(0); STAGE_B(0);
    STAGE_A(1); STAGE_B(1);
    STAGE_A(2); STAGE_B(2);

    f32x4 acc[8][4] = {};
    for (int t = 0; t < NT; ++t) {
        const int slot = t & 3;
        if (t <= NT - 3)      asm volatile("s_waitcnt vmcnt(8)" ::: "memory");
        else if (t == NT - 2) asm volatile("s_waitcnt vmcnt(4)" ::: "memory");
        else                  asm volatile("s_waitcnt vmcnt(0)" ::: "memory");
        __builtin_amdgcn_s_barrier();
        __builtin_amdgcn_sched_barrier(0);

        const u16* Ab = &smem.k.A[slot][(wm * 8) * 512];
        const u16* Bb = &smem.k.B[slot][(wn * 4) * 512];

        if (t + 3 < NT) STAGE_A(t + 3);
        short8 bf[4], af[4];
#pragma unroll
        for (int n = 0; n < 4; ++n) bf[n] = *(const short8*)(Bb + n * 512 + lane * 8);
#pragma unroll
        for (int m = 0; m < 4; ++m) af[m] = *(const short8*)(Ab + m * 512 + lane * 8);
        __builtin_amdgcn_s_setprio(1);
#pragma unroll
        for (int m = 0; m < 4; ++m)
#pragma unroll
            for (int n = 0; n < 4; ++n)
                acc[m][n] = mfma16(af[m], bf[n], acc[m][n]);
        __builtin_amdgcn_s_setprio(0);

        if (t + 3 < NT) STAGE_B(t + 3);
#pragma unroll
        for (int m = 0; m < 4; ++m) af[m] = *(const short8*)(Ab + (4 + m) * 512 + lane * 8);
        __builtin_amdgcn_s_setprio(1);
#pragma unroll
        for (int m = 0; m < 4; ++m)
#pragma unroll
            for (int n = 0; n < 4; ++n)
                acc[4 + m][n] = mfma16(af[m], bf[n], acc[4 + m][n]);
        __builtin_amdgcn_s_setprio(0);
    }
#undef STAGE_A
#undef STAGE_B

    // -------- epilogue: 4 strips of 64 rows via LDS, coalesced vector stores ----
    const bool vpath = VSPLIT && (col0 >= 2048);
    __syncthreads();
#pragma unroll
    for (int s = 0; s < 4; ++s) {
        if (s) __syncthreads();
        if (wm == (s >> 1)) {
            const int mb4 = (s & 1) * 4;
#pragma unroll
            for (int mm = 0; mm < 4; ++mm)
#pragma unroll
                for (int n = 0; n < 4; ++n) {
                    int c = wn * 64 + n * 16 + l15;
                    float bv = BIAS ? bias[col0 + c] : 0.f;
#pragma unroll
                    for (int j = 0; j < 4; ++j) {
                        int lr = mm * 16 + lg * 4 + j;
                        float v = acc[mb4 + mm][n][j] + bv;
                        if (RELU) v = fmaxf(v, 0.f);
                        if (vpath)         smem.vt[c * 66 + lr] = f2bf(v);
                        else if (OUT_BF16) smem.ob[lr * 264 + c] = f2bf(v);
                        else               smem.of[lr * 268 + c] = v;
                    }
                }
        }
        __syncthreads();
        const int gr0 = row0 + s * 64;
        if (vpath) {
            const int bb = gr0 >> 10;        // batch (256-row tiles never cross)
            const int mb = gr0 & 1023;       // m base within sequence
#pragma unroll
            for (int it = 0; it < 4; ++it) {
                int idx = it * 512 + tid;    // 2048 segs: dc in [0,256), mseg in [0,8)
                int dc = idx >> 3, mseg = idx & 7;
                int hh = (col0 - 2048 + dc) >> 7;
                int dd = (col0 - 2048 + dc) & 127;
                *(short8*)(Vt + ((size_t)(bb * 8 + hh)) * (HDIM * SEQ)
                              + (size_t)dd * SEQ + mb + mseg * 8) =
                    *(const short8*)(&smem.vt[dc * 66 + mseg * 8]);
            }
        } else if (OUT_BF16) {
#pragma unroll
            for (int it = 0; it < 4; ++it) {
                int idx = it * 512 + tid;          // 2048 segs of 8 u16
                int r = idx >> 5, seg = idx & 31;
                *(short8*)((u16*)C + (size_t)(gr0 + r) * N + col0 + seg * 8) =
                    *(const short8*)(&smem.ob[r * 264 + seg * 8]);
            }
        } else {
#pragma unroll
            for (int it = 0; it < 8; ++it) {
                int idx = it * 512 + tid;          // 4096 segs of 4 f32
                int r = idx >> 6, seg = idx & 63;
                *(f32x4*)((float*)C + (size_t)(gr0 + r) * N + col0 + seg * 4) =
                    *(const f32x4*)(&smem.of[r * 268 + seg * 4]);
            }
        }
    }
}

// ---------------- attention: 4 waves x 32 q-rows, swapped-QK, in-register P ---
// R5: restored R2 structure (measured best).  Normalization folded into the
// exponent: P = exp2(fma(s, C, -log2(rs))) — removes 16 v_mul/tile (pass B).
__global__ __launch_bounds__(256, 3) void k_attn(const u16* __restrict__ QKV,
                                                 const u16* __restrict__ Vt,
                                                 u16* __restrict__ O,
                                                 float* __restrict__ csp) {
    union Sm {
        u16 K2[2][8192];                                   // pass A: 64-key dbuf (32KB)
        struct { u16 Kl[2][4096]; u16 Vl[2][4096]; } pb;   // pass B: 32-key dbufs
    };
    __shared__ Sm sm;
    __shared__ float cs[1024];       // column sums (4KB)
    const int id = blockIdx.x;
    const int id2 = (id & 7) * 256 + (id >> 3);   // bijective, 2048 = 8*256
    const int qt = id2 & 7, bh = id2 >> 3;
    const int b = bh >> 3, h = bh & 7;
    const int tid = threadIdx.x, lane = tid & 63, wv = tid >> 6;  // wv in [0,4)
    const int l15 = lane & 15, lg = lane >> 4;

    for (int i = tid; i < 1024; i += 256) cs[i] = 0.f;

    const int q0 = qt * 128 + wv * 32;           // this wave's 32 q-rows
    const u16* qbaseA = QKV + (size_t)(b * SEQ + q0 + l15) * QSTR + h * HDIM + lg * 8;
    const u16* qbaseB = qbaseA + (size_t)16 * QSTR;
    short8 qfA[4], qfB[4];
#pragma unroll
    for (int kk = 0; kk < 4; ++kk) {
        qfA[kk] = *(const short8*)(qbaseA + kk * 32);
        qfB[kk] = *(const short8*)(qbaseB + kk * 32);
    }
    const float CEXP = 0.12751743f;   // (1/sqrt(128)) * log2(e)
    const u16* kbase = QKV + (size_t)(b * SEQ) * QSTR + 1024 + h * HDIM;
    const u16* vtb = Vt + (size_t)bh * HDIM * SEQ;

    // pass A: wave wv stages 4 chunks (its 16 keys, all d) of the 64-key tile
#define STAGE_K2(tt) { _Pragma("unroll")                                        \
    for (int i = 0; i < 4; ++i) {                                               \
        gload_lds16(kbase + (size_t)((tt) * 64 + wv * 16 + l15) * QSTR          \
                    + i * 32 + lg * 8, &sm.K2[(tt) & 1][(wv * 4 + i) * 512]); } }
    // pass B: wave wv stages chunks 2wv, 2wv+1 (of 8) each 32-key tile
#define STAGE_K(tt) { _Pragma("unroll")                                         \
    for (int i = 0; i < 2; ++i) { int c = wv * 2 + i;                           \
        gload_lds16(kbase + (size_t)((tt) * 32 + (c >> 2) * 16 + l15) * QSTR    \
                    + (c & 3) * 32 + lg * 8, &sm.pb.Kl[(tt) & 1][c * 512]); } }
#define STAGE_V(tt) { _Pragma("unroll")                                         \
    for (int i = 0; i < 2; ++i) { int c = wv * 2 + i;                           \
        gload_lds16(vtb + (size_t)(c * 16 + l15) * SEQ + (tt) * 32 + lg * 8,    \
                    &sm.pb.Vl[(tt) & 1][c * 512]); } }

    // ---------------- pass A: per-q rowsums of exp2(s*C), 64-key tiles ---------
    STAGE_K2(0);
    asm volatile("s_waitcnt vmcnt(0)" ::: "memory");
    __builtin_amdgcn_s_barrier();
    f32x4 rsA4 = {0.f, 0.f, 0.f, 0.f}, rsB4 = {0.f, 0.f, 0.f, 0.f};
    for (int t = 0; t < 16; ++t) {
        if (t < 15) STAGE_K2(t + 1);
        const u16* Kp = &sm.K2[t & 1][0];
        __builtin_amdgcn_s_setprio(1);
#pragma unroll
        for (int j = 0; j < 4; j += 2) {
            f32x4 s0 = {0.f,0.f,0.f,0.f}, s1 = {0.f,0.f,0.f,0.f};
            f32x4 s2 = {0.f,0.f,0.f,0.f}, s3 = {0.f,0.f,0.f,0.f};
#pragma unroll
            for (int kk = 0; kk < 4; ++kk) {
                short8 k0 = *(const short8*)(Kp + (j * 4 + kk) * 512 + lane * 8);
                short8 k1 = *(const short8*)(Kp + ((j + 1) * 4 + kk) * 512 + lane * 8);
                s0 = mfma16(k0, qfA[kk], s0);
                s1 = mfma16(k0, qfB[kk], s1);
                s2 = mfma16(k1, qfA[kk], s2);
                s3 = mfma16(k1, qfB[kk], s3);
            }
#pragma unroll
            for (int r = 0; r < 4; ++r) {
                rsA4[r] += __builtin_amdgcn_exp2f(s0[r] * CEXP)
                         + __builtin_amdgcn_exp2f(s2[r] * CEXP);
                rsB4[r] += __builtin_amdgcn_exp2f(s1[r] * CEXP)
                         + __builtin_amdgcn_exp2f(s3[r] * CEXP);
            }
        }
        __builtin_amdgcn_s_setprio(0);
        asm volatile("s_waitcnt vmcnt(0)" ::: "memory");
        __builtin_amdgcn_s_barrier();
    }
    float rsA = (rsA4[0] + rsA4[1]) + (rsA4[2] + rsA4[3]);
    float rsB = (rsB4[0] + rsB4[1]) + (rsB4[2] + rsB4[3]);
    rsA += __shfl_xor(rsA, 16); rsA += __shfl_xor(rsA, 32);
    rsB += __shfl_xor(rsB, 16); rsB += __shfl_xor(rsB, 32);
    // fold normalization into the exponent: exp2(s*C)/rs = exp2(s*C - log2(rs))
    const float lgA = __builtin_amdgcn_logf(rsA);
    const float lgB = __builtin_amdgcn_logf(rsB);

    // ---------------- pass B: P = exp2(sC - log2 rs) ; O += P V ; column sums --
    STAGE_K(0); STAGE_V(0);
    asm volatile("s_waitcnt vmcnt(0)" ::: "memory");
    __builtin_amdgcn_s_barrier();
    f32x4 odA[8] = {}, odB[8] = {};
    for (int t = 0; t < 32; ++t) {
        const int m0 = t * 32;
        if (t < 31) { STAGE_K(t + 1); STAGE_V(t + 1); }
        const u16* Kp = &sm.pb.Kl[t & 1][0];
        f32x4 sA0 = {0.f,0.f,0.f,0.f}, sA1 = {0.f,0.f,0.f,0.f};
        f32x4 sB0 = {0.f,0.f,0.f,0.f}, sB1 = {0.f,0.f,0.f,0.f};
        __builtin_amdgcn_s_setprio(1);
#pragma unroll
        for (int kk = 0; kk < 4; ++kk) {
            short8 k0 = *(const short8*)(Kp + kk * 512 + lane * 8);
            short8 k1 = *(const short8*)(Kp + (4 + kk) * 512 + lane * 8);
            sA0 = mfma16(k0, qfA[kk], sA0);
            sA1 = mfma16(k1, qfA[kk], sA1);
            sB0 = mfma16(k0, qfB[kk], sB0);
            sB1 = mfma16(k1, qfB[kk], sB1);
        }
        __builtin_amdgcn_s_setprio(0);
        f32x4 pA0, pA1, pB0, pB1;
#pragma unroll
        for (int r = 0; r < 4; ++r) {
            pA0[r] = __builtin_amdgcn_exp2f(__builtin_fmaf(sA0[r], CEXP, -lgA));
            pA1[r] = __builtin_amdgcn_exp2f(__builtin_fmaf(sA1[r], CEXP, -lgA));
            pB0[r] = __builtin_amdgcn_exp2f(__builtin_fmaf(sB0[r], CEXP, -lgB));
            pB1[r] = __builtin_amdgcn_exp2f(__builtin_fmaf(sB1[r], CEXP, -lgB));
        }
        // column sums: DPP full-row reduce over the 16 q-lanes
        float csv[8];
#pragma unroll
        for (int r = 0; r < 4; ++r) {
            csv[r]     = pA0[r] + pB0[r];
            csv[4 + r] = pA1[r] + pB1[r];
        }
#pragma unroll
        for (int j2 = 0; j2 < 8; ++j2) {
            DPP_RORADD(csv[j2], 0x128);
            DPP_RORADD(csv[j2], 0x124);
            DPP_RORADD(csv[j2], 0x122);
            DPP_RORADD(csv[j2], 0x121);
        }
        float cval = csv[0];
        cval = (l15 == 1) ? csv[1] : cval;
        cval = (l15 == 2) ? csv[2] : cval;
        cval = (l15 == 3) ? csv[3] : cval;
        cval = (l15 == 4) ? csv[4] : cval;
        cval = (l15 == 5) ? csv[5] : cval;
        cval = (l15 == 6) ? csv[6] : cval;
        cval = (l15 == 7) ? csv[7] : cval;
        if (l15 < 8) {
            int mw = (l15 < 4) ? (lg * 4 + l15) : (16 + lg * 4 + (l15 - 4));
            atomicAdd(&cs[m0 + mw], cval);
        }
        // P -> PV A-fragments, in registers
        short8 paA = p2frag(pA0, pA1, lane);
        short8 paB = p2frag(pB0, pB1, lane);
        const u16* Vb_ = &sm.pb.Vl[t & 1][0];
        __builtin_amdgcn_s_setprio(1);
#pragma unroll
        for (int db = 0; db < 8; ++db) {
            short8 vf = *(const short8*)(Vb_ + db * 512 + lane * 8);
            odA[db] = mfma16(paA, vf, odA[db]);
            odB[db] = mfma16(paB, vf, odB[db]);
        }
        __builtin_amdgcn_s_setprio(0);
        asm volatile("s_waitcnt vmcnt(0)" ::: "memory");
        __builtin_amdgcn_s_barrier();
    }
#undef STAGE_K2
#undef STAGE_K
#undef STAGE_V
    __syncthreads();   // make all waves' cs atomics visible before drain
    u16* obA = O + (size_t)(b * SEQ + q0 + lg * 4) * DIMC + h * HDIM + l15;
    u16* obB = obA + (size_t)16 * DIMC;
#pragma unroll
    for (int db = 0; db < 8; ++db)
#pragma unroll
        for (int r = 0; r < 4; ++r) {
            obA[(size_t)r * DIMC + db * 16] = f2bf(odA[db][r]);
            obB[(size_t)r * DIMC + db * 16] = f2bf(odB[db][r]);
        }
    for (int m = tid; m < 1024; m += 256)
        csp[((size_t)bh * 8 + qt) * 1024 + m] = cs[m];
}

// ---------------- LN1: LN(x_f32 + proj_bf16) -> bf16 out ----------------
__global__ __launch_bounds__(256) void k_ln1(const float* __restrict__ xa,
                                             const u16* __restrict__ pj,
                                             const float* __restrict__ g,
                                             const float* __restrict__ bt,
                                             u16* __restrict__ ob) {
    const int row = blockIdx.x;
    const int t = threadIdx.x, lane = t & 63, wv = t >> 6;
    f32x4 va = ((const f32x4*)(xa + (size_t)row * DIMC))[t];
    short4v hv = ((const short4v*)(pj + (size_t)row * DIMC))[t];
    f32x4 s;
#pragma unroll
    for (int j = 0; j < 4; ++j) s[j] = va[j] + bf2f((u16)hv[j]);
    float sum = s[0] + s[1] + s[2] + s[3];
    float sq = s[0]*s[0] + s[1]*s[1] + s[2]*s[2] + s[3]*s[3];
#pragma unroll
    for (int o = 1; o < 64; o <<= 1) { sum += __shfl_xor(sum, o); sq += __shfl_xor(sq, o); }
    __shared__ float red[8];
    if (lane == 0) { red[wv] = sum; red[4 + wv] = sq; }
    __syncthreads();
    sum = red[0] + red[1] + red[2] + red[3];
    sq  = red[4] + red[5] + red[6] + red[7];
    float mu = sum * (1.f / DIMC);
    float rstd = rsqrtf(sq * (1.f / DIMC) - mu * mu + 1e-5f);
    f32x4 gg = ((const f32x4*)g)[t];
    f32x4 bb = ((const f32x4*)bt)[t];
    uint32_t lo, hi;
    float o0 = (s[0] - mu) * rstd * gg[0] + bb[0];
    float o1 = (s[1] - mu) * rstd * gg[1] + bb[1];
    float o2 = (s[2] - mu) * rstd * gg[2] + bb[2];
    float o3 = (s[3] - mu) * rstd * gg[3] + bb[3];
    lo = f2bf(o0) | ((uint32_t)f2bf(o1) << 16);
    hi = f2bf(o2) | ((uint32_t)f2bf(o3) << 16);
    ((uint2*)(ob + (size_t)row * DIMC))[t] = make_uint2(lo, hi);
}

// ---------------- LN2: LN(h_bf16 + ff2_bf16) -> fp32 out ----------------
__global__ __launch_bounds__(256) void k_ln2(const u16* __restrict__ xa,
                                             const u16* __restrict__ f2,
                                             const float* __restrict__ g,
                                             const float* __restrict__ bt,
                                             float* __restrict__ of) {
    const int row = blockIdx.x;
    const int t = threadIdx.x, lane = t & 63, wv = t >> 6;
    short4v hv = ((const short4v*)(xa + (size_t)row * DIMC))[t];
    short4v fv = ((const short4v*)(f2 + (size_t)row * DIMC))[t];
    f32x4 s;
#pragma unroll
    for (int j = 0; j < 4; ++j) s[j] = bf2f((u16)hv[j]) + bf2f((u16)fv[j]);
    float sum = s[0] + s[1] + s[2] + s[3];
    float sq = s[0]*s[0] + s[1]*s[1] + s[2]*s[2] + s[3]*s[3];
#pragma unroll
    for (int o = 1; o < 64; o <<= 1) { sum += __shfl_xor(sum, o); sq += __shfl_xor(sq, o); }
    __shared__ float red[8];
    if (lane == 0) { red[wv] = sum; red[4 + wv] = sq; }
    __syncthreads();
    sum = red[0] + red[1] + red[2] + red[3];
    sq  = red[4] + red[5] + red[6] + red[7];
    float mu = sum * (1.f / DIMC);
    float rstd = rsqrtf(sq * (1.f / DIMC) - mu * mu + 1e-5f);
    f32x4 gg = ((const f32x4*)g)[t];
    f32x4 bb = ((const f32x4*)bt)[t];
    f32x4 o4;
#pragma unroll
    for (int j = 0; j < 4; ++j) o4[j] = (s[j] - mu) * rstd * gg[j] + bb[j];
    ((f32x4*)(of + (size_t)row * DIMC))[t] = o4;
}

// ---------------- halting: reduce column-sum partials, /H, softmax, add --------
__global__ __launch_bounds__(256) void k_halt(const float* __restrict__ csp,
                                              const float* __restrict__ hs,
                                              float* __restrict__ halt_out,
                                              float* __restrict__ a_out) {
    const int b = blockIdx.x, t = threadIdx.x, lane = t & 63, wv = t >> 6;
    const float* base = csp + (size_t)b * 65536;   // 8 h * 8 qt * 1024
    float acc[4] = {0.f, 0.f, 0.f, 0.f};
    for (int s2 = 0; s2 < 64; ++s2) {
#pragma unroll
        for (int j = 0; j < 4; ++j) acc[j] += base[(size_t)s2 * 1024 + j * 256 + t];
    }
    float mx = -1e30f;
#pragma unroll
    for (int j = 0; j < 4; ++j) { acc[j] *= 0.125f; mx = fmaxf(mx, acc[j]); }
#pragma unroll
    for (int o = 1; o < 64; o <<= 1) mx = fmaxf(mx, __shfl_xor(mx, o));
    __shared__ float red[8];
    if (lane == 0) red[wv] = mx;
    __syncthreads();
    mx = fmaxf(fmaxf(red[0], red[1]), fmaxf(red[2], red[3]));
    float e[4]; float sum = 0.f;
#pragma unroll
    for (int j = 0; j < 4; ++j) { e[j] = __expf(acc[j] - mx); sum += e[j]; }
#pragma unroll
    for (int o = 1; o < 64; o <<= 1) sum += __shfl_xor(sum, o);
    if (lane == 0) red[4 + wv] = sum;
    __syncthreads();
    sum = red[4] + red[5] + red[6] + red[7];
    float inv = 1.f / sum;
#pragma unroll
    for (int j = 0; j < 4; ++j) {
        int m = j * 256 + t;
        float a = e[j] * inv;
        a_out[b * SEQ + m] = a;
        halt_out[b * SEQ + m] = hs[b * SEQ + m] + a;
    }
}

// =======================================================================
// workspace layout (<= 352 MiB):
//   [0,64)    xb -> o_b -> hb
//   [64,256)  qkv bf16 (192MB; V-third never written) -> proj bf16 [64,128)
//             -> ff1 bf16 [64,192); ff2 bf16 [192,224)
//   [256,320) Vt (written by QKV gemm epilogue)
//   [320,344) transposed bf16 weights (WqkvT 6MB | WpT 2MB | W1T 8MB | W2T 8MB)
//   [344,352) colsum partials
// =======================================================================
extern "C" void kernel_launch(void* const* d_in, const int* in_sizes, int n_in,
                              void* d_out, int out_size, void* d_ws, size_t ws_size,
                              hipStream_t stream) {
    (void)in_sizes; (void)n_in; (void)out_size; (void)ws_size;
    const float* x   = (const float*)d_in[0];
    const float* hs  = (const float*)d_in[1];
    const float* Wq  = (const float*)d_in[2];
    const float* Wkv = (const float*)d_in[3];
    const float* Wp  = (const float*)d_in[4];
    const float* bp  = (const float*)d_in[5];
    const float* W1  = (const float*)d_in[6];
    const float* b1  = (const float*)d_in[7];
    const float* W2  = (const float*)d_in[8];
    const float* b2  = (const float*)d_in[9];
    const float* g1  = (const float*)d_in[10];
    const float* be1 = (const float*)d_in[11];
    const float* g2  = (const float*)d_in[12];
    const float* be2 = (const float*)d_in[13];

    float* out = (float*)d_out;
    float* halt_out = out + (size_t)SROWS * DIMC;
    float* a_out = halt_out + SROWS;

    char* w = (char*)d_ws;
    const size_t MB = 1024 * 1024;
    u16*  xb    = (u16*)(w);
    u16*  qkv   = (u16*)(w + 64 * MB);
    u16*  Vt    = (u16*)(w + 256 * MB);
    u16*  WqkvT = (u16*)(w + 320 * MB);
    u16*  WpT   = (u16*)(w + 326 * MB);
    u16*  W1T   = (u16*)(w + 328 * MB);
    u16*  W2T   = (u16*)(w + 336 * MB);
    float* csp  = (float*)(w + 344 * MB);
    u16*  o_b   = (u16*)(w);                // reuse xb (dead after QKV gemm)
    u16*  projb = (u16*)(w + 64 * MB);      // bf16, over qkv Q-third (dead after attn)
    u16*  hb    = (u16*)(w);                // reuse o_b (dead after proj)
    u16*  ff1   = (u16*)(w + 64 * MB);      // over projb (dead after LN1)
    u16*  ff2b  = (u16*)(w + 192 * MB);     // bf16, over qkv tail

    dim3 tb(32, 8);
    // casts + weight transposes (Wq and Wkv land in one contiguous WqkvT)
    k_cast<<<SROWS * DIMC / 4 / 256, 256, 0, stream>>>(x, xb, SROWS * DIMC / 4);
    k_transpose_cast<<<dim3(DIMC / 32, DIMC / 32), tb, 0, stream>>>(Wq, WqkvT, DIMC, DIMC);
    k_transpose_cast<<<dim3(2 * DIMC / 32, DIMC / 32), tb, 0, stream>>>(
        Wkv, WqkvT + (size_t)DIMC * DIMC, DIMC, 2 * DIMC);
    k_transpose_cast<<<dim3(DIMC / 32, DIMC / 32), tb, 0, stream>>>(Wp, WpT, DIMC, DIMC);
    k_transpose_cast<<<dim3(FFND / 32, DIMC / 32), tb, 0, stream>>>(W1, W1T, DIMC, FFND);
    k_transpose_cast<<<dim3(DIMC / 32, FFND / 32), tb, 0, stream>>>(W2, W2T, FFND, DIMC);
    // fused QKV gemm (N = 3072); V columns written transposed into Vt
    k_gemm256<true, false, false, true><<<dim3(QSTR / 256, SROWS / 256), 512, 0, stream>>>(
        xb, WqkvT, nullptr, qkv, Vt, SROWS, QSTR, DIMC);
    // attention (256 threads: 4 waves x 32 q-rows)
    k_attn<<<2048, 256, 0, stream>>>(qkv, Vt, o_b, csp);
    // output projection (+bp) -> bf16
    k_gemm256<true, false, true, false><<<dim3(DIMC / 256, SROWS / 256), 512, 0, stream>>>(
        o_b, WpT, bp, projb, nullptr, SROWS, DIMC, DIMC);
    // LN1: h = LN(x + proj) -> bf16 hb
    k_ln1<<<SROWS, 256, 0, stream>>>(x, projb, g1, be1, hb);
    // FFN in 2 row chunks of 16384
    for (int c = 0; c < 2; ++c) {
        const size_t ro = (size_t)c * 16384;
        k_gemm256<true, true, true, false><<<dim3(FFND / 256, 16384 / 256), 512, 0, stream>>>(
            hb + ro * DIMC, W1T, b1, ff1, nullptr, 16384, FFND, DIMC);
        k_gemm256<true, false, true, false><<<dim3(DIMC / 256, 16384 / 256), 512, 0, stream>>>(
            ff1, W2T, b2, ff2b, nullptr, 16384, DIMC, FFND);
        k_ln2<<<16384, 256, 0, stream>>>(hb + ro * DIMC, ff2b, g2, be2, out + ro * DIMC);
    }
    // halting score
    k_halt<<<BATCH, 256, 0, stream>>>(csp, hs, halt_out, a_out);
}

// Round 7
// 1432.020 us; speedup vs baseline: 1.0848x; 1.0068x over previous
//
#include <hip/hip_runtime.h>
#include <hip/hip_bf16.h>
#include <stdint.h>

// ---------------- problem constants ----------------
#define DIMC 1024
#define HEADS 8
#define HDIM 128
#define FFND 4096
#define BATCH 32
#define SEQ 1024
#define SROWS (BATCH*SEQ)          // 32768
#define QSTR 3072                  // fused qkv row stride

typedef unsigned short u16;
typedef short short4v __attribute__((ext_vector_type(4)));
typedef short short8 __attribute__((ext_vector_type(8)));
typedef float f32x4 __attribute__((ext_vector_type(4)));
typedef __bf16 bf16x8 __attribute__((ext_vector_type(8)));
typedef unsigned uintv2 __attribute__((ext_vector_type(2)));

// fp32 -> bf16 round-to-nearest-even
__device__ __forceinline__ u16 f2bf(float f) {
    union { float f; uint32_t u; } x{f};
    uint32_t r = x.u + 0x7FFFu + ((x.u >> 16) & 1u);
    return (u16)(r >> 16);
}
__device__ __forceinline__ float bf2f(u16 h) {
    union { uint32_t u; float f; } x;
    x.u = ((uint32_t)h) << 16;
    return x.f;
}

__device__ __forceinline__ f32x4 mfma16(short8 a, short8 b, f32x4 c) {
    return __builtin_amdgcn_mfma_f32_16x16x32_bf16(
        __builtin_bit_cast(bf16x8, a), __builtin_bit_cast(bf16x8, b), c, 0, 0, 0);
}

// async global->LDS, 16 bytes per lane; lds must be the wave-uniform base
__device__ __forceinline__ void gload_lds16(const u16* g, u16* lds) {
    __builtin_amdgcn_global_load_lds(
        (const __attribute__((address_space(1))) uint32_t*)g,
        (__attribute__((address_space(3))) uint32_t*)lds, 16, 0, 0);
}

// DPP rotate-add within 16-lane row (full 16-lane sum via 8,4,2,1)
#define DPP_RORADD(x, ctrl) do {                                               \
    int _t = __builtin_amdgcn_mov_dpp(__builtin_bit_cast(int, (x)), (ctrl),    \
                                      0xf, 0xf, true);                         \
    (x) += __builtin_bit_cast(float, _t); } while (0)

// P (normalized, f32, swapped-QK layout: q=l15, m=(lg,reg)) -> PV A-fragment
// (q=l15, k-elems m=8*lg..8*lg+7) purely in registers. p0 = m-subtile 0-15,
// p1 = m-subtile 16-31 of the 32-key chunk.
// R7: lane redistribution via permlane{32,16}_swap (VALU) instead of
// ds_bpermute shfl_xor (DS pipe) — verified lane-algebra identical.
__device__ __forceinline__ short8 p2frag(f32x4 p0, f32x4 p1, int lane) {
    uint32_t a, b, c, d;
    asm("v_cvt_pk_bf16_f32 %0, %1, %2" : "=v"(a) : "v"(p0[0]), "v"(p0[1]));
    asm("v_cvt_pk_bf16_f32 %0, %1, %2" : "=v"(b) : "v"(p0[2]), "v"(p0[3]));
    asm("v_cvt_pk_bf16_f32 %0, %1, %2" : "=v"(c) : "v"(p1[0]), "v"(p1[1]));
    asm("v_cvt_pk_bf16_f32 %0, %1, %2" : "=v"(d) : "v"(p1[2]), "v"(p1[3]));
    uint32_t P, Q, R, S;
#if __has_builtin(__builtin_amdgcn_permlane32_swap)
    {
        uintv2 pq = __builtin_amdgcn_permlane32_swap(a, c, false, false);
        uintv2 rs = __builtin_amdgcn_permlane32_swap(b, d, false, false);
        P = pq[0]; Q = pq[1]; R = rs[0]; S = rs[1];
    }
#else
    {
        uint32_t ax = (uint32_t)__shfl_xor((int)a, 32);
        uint32_t bx = (uint32_t)__shfl_xor((int)b, 32);
        uint32_t cx = (uint32_t)__shfl_xor((int)c, 32);
        uint32_t dx = (uint32_t)__shfl_xor((int)d, 32);
        const bool up = (lane & 32) != 0;
        P = up ? cx : a; Q = up ? c : ax;
        R = up ? dx : b; S = up ? d : bx;
    }
#endif
    uint32_t w0, w1, w2, w3;
#if __has_builtin(__builtin_amdgcn_permlane16_swap)
    {
        uintv2 w02 = __builtin_amdgcn_permlane16_swap(P, Q, false, false);
        uintv2 w13 = __builtin_amdgcn_permlane16_swap(R, S, false, false);
        w0 = w02[0]; w2 = w02[1]; w1 = w13[0]; w3 = w13[1];
    }
#else
    {
        uint32_t Px = (uint32_t)__shfl_xor((int)P, 16);
        uint32_t Qx = (uint32_t)__shfl_xor((int)Q, 16);
        uint32_t Rx = (uint32_t)__shfl_xor((int)R, 16);
        uint32_t Sx = (uint32_t)__shfl_xor((int)S, 16);
        const bool odd = (lane & 16) != 0;
        w0 = odd ? Qx : P;  w1 = odd ? Sx : R;
        w2 = odd ? Q  : Px; w3 = odd ? S  : Rx;
    }
#endif
    union { uint32_t w[4]; short8 s; } u;
    u.w[0] = w0; u.w[1] = w1; u.w[2] = w2; u.w[3] = w3;
    return u.s;
}

// ---------------- cast fp32 -> bf16 (vectorized) ----------------
__global__ __launch_bounds__(256) void k_cast(const float* __restrict__ in,
                                              u16* __restrict__ out, int n4) {
    int i = blockIdx.x * 256 + threadIdx.x;
    if (i < n4) {
        f32x4 v = ((const f32x4*)in)[i];
        uint32_t lo = f2bf(v[0]) | ((uint32_t)f2bf(v[1]) << 16);
        uint32_t hi = f2bf(v[2]) | ((uint32_t)f2bf(v[3]) << 16);
        ((uint2*)out)[i] = make_uint2(lo, hi);
    }
}

// ---------------- W (K x N fp32) -> Wt (N x K bf16), tiled ----------------
__global__ __launch_bounds__(256) void k_transpose_cast(const float* __restrict__ W,
                                                        u16* __restrict__ Wt,
                                                        int K, int N) {
    __shared__ u16 tile[32][33];
    int n0 = blockIdx.x * 32, k0 = blockIdx.y * 32;
    int tx = threadIdx.x, ty = threadIdx.y;   // 32 x 8
#pragma unroll
    for (int i = 0; i < 32; i += 8)
        tile[ty + i][tx] = f2bf(W[(size_t)(k0 + ty + i) * N + n0 + tx]);
    __syncthreads();
#pragma unroll
    for (int i = 0; i < 32; i += 8)
        Wt[(size_t)(n0 + ty + i) * K + k0 + tx] = tile[tx][ty + i];
}

// ---------------- GEMM 256x256, BK=32, 4-slot ring, counted vmcnt -------------
// R7: A-operand row stride `lda` decoupled from K (lets attn-O live inside
// the qkv buffer's V-third).
template<bool OUT_BF16, bool RELU, bool BIAS, bool VSPLIT>
__global__ __launch_bounds__(512, 2) void k_gemm256(const u16* __restrict__ A,
                                                    const u16* __restrict__ Bt,
                                                    const float* __restrict__ bias,
                                                    void* __restrict__ C,
                                                    u16* __restrict__ Vt,
                                                    int M, int N, int K, int lda) {
    union Smem {
        struct { u16 A[4][8192]; u16 B[4][8192]; } k;   // 128KB ring
        u16 ob[64 * 264];                                // bf16 strip (33KB)
        float of[64 * 268];                              // fp32 strip (69KB)
        u16 vt[256 * 66];                                // transposed strip (33KB)
    };
    __shared__ Smem smem;
    const int tid = threadIdx.x;
    const int lane = tid & 63, wv = tid >> 6;
    const int wm = wv >> 2, wn = wv & 3;
    const int l15 = lane & 15, lg = lane >> 4;
    // XCD-aware bijective swizzle (requires nwg % 8 == 0 — all our grids comply)
    const int gx = gridDim.x;
    const int nwg = gx * gridDim.y;
    const int id = blockIdx.y * gx + blockIdx.x;
    const int id2 = (id & 7) * (nwg >> 3) + (id >> 3);
    const int row0 = (id2 / gx) << 8, col0 = (id2 % gx) << 8;
    const int NT = K >> 5;

#define STAGE_A(tt) {                                                          \
    int _t = (tt);                                                             \
    _Pragma("unroll")                                                          \
    for (int i = 0; i < 2; ++i) {                                              \
        int blk = wv * 2 + i;                                                  \
        gload_lds16(A + (size_t)(row0 + blk * 16 + l15) * lda + _t * 32 + lg * 8,\
                    &smem.k.A[_t & 3][blk * 512]);                             \
    } }
#define STAGE_B(tt) {                                                          \
    int _t = (tt);                                                             \
    _Pragma("unroll")                                                          \
    for (int i = 0; i < 2; ++i) {                                              \
        int blk = wv * 2 + i;                                                  \
        gload_lds16(Bt + (size_t)(col0 + blk * 16 + l15) * K + _t * 32 + lg * 8,\
                    &smem.k.B[_t & 3][blk * 512]);                             \
    } }

    STAGE_A(0); STAGE_B(0);
    STAGE_A(1); STAGE_B(1);
    STAGE_A(2); STAGE_B(2);

    f32x4 acc[8][4] = {};
    for (int t = 0; t < NT; ++t) {
        const int slot = t & 3;
        if (t <= NT - 3)      asm volatile("s_waitcnt vmcnt(8)" ::: "memory");
        else if (t == NT - 2) asm volatile("s_waitcnt vmcnt(4)" ::: "memory");
        else                  asm volatile("s_waitcnt vmcnt(0)" ::: "memory");
        __builtin_amdgcn_s_barrier();
        __builtin_amdgcn_sched_barrier(0);

        const u16* Ab = &smem.k.A[slot][(wm * 8) * 512];
        const u16* Bb = &smem.k.B[slot][(wn * 4) * 512];

        if (t + 3 < NT) STAGE_A(t + 3);
        short8 bf[4], af[4];
#pragma unroll
        for (int n = 0; n < 4; ++n) bf[n] = *(const short8*)(Bb + n * 512 + lane * 8);
#pragma unroll
        for (int m = 0; m < 4; ++m) af[m] = *(const short8*)(Ab + m * 512 + lane * 8);
        __builtin_amdgcn_s_setprio(1);
#pragma unroll
        for (int m = 0; m < 4; ++m)
#pragma unroll
            for (int n = 0; n < 4; ++n)
                acc[m][n] = mfma16(af[m], bf[n], acc[m][n]);
        __builtin_amdgcn_s_setprio(0);

        if (t + 3 < NT) STAGE_B(t + 3);
#pragma unroll
        for (int m = 0; m < 4; ++m) af[m] = *(const short8*)(Ab + (4 + m) * 512 + lane * 8);
        __builtin_amdgcn_s_setprio(1);
#pragma unroll
        for (int m = 0; m < 4; ++m)
#pragma unroll
            for (int n = 0; n < 4; ++n)
                acc[4 + m][n] = mfma16(af[m], bf[n], acc[4 + m][n]);
        __builtin_amdgcn_s_setprio(0);
    }
#undef STAGE_A
#undef STAGE_B

    // -------- epilogue: 4 strips of 64 rows via LDS, coalesced vector stores ----
    const bool vpath = VSPLIT && (col0 >= 2048);
    __syncthreads();
#pragma unroll
    for (int s = 0; s < 4; ++s) {
        if (s) __syncthreads();
        if (wm == (s >> 1)) {
            const int mb4 = (s & 1) * 4;
#pragma unroll
            for (int mm = 0; mm < 4; ++mm)
#pragma unroll
                for (int n = 0; n < 4; ++n) {
                    int c = wn * 64 + n * 16 + l15;
                    float bv = BIAS ? bias[col0 + c] : 0.f;
#pragma unroll
                    for (int j = 0; j < 4; ++j) {
                        int lr = mm * 16 + lg * 4 + j;
                        float v = acc[mb4 + mm][n][j] + bv;
                        if (RELU) v = fmaxf(v, 0.f);
                        if (vpath)         smem.vt[c * 66 + lr] = f2bf(v);
                        else if (OUT_BF16) smem.ob[lr * 264 + c] = f2bf(v);
                        else               smem.of[lr * 268 + c] = v;
                    }
                }
        }
        __syncthreads();
        const int gr0 = row0 + s * 64;
        if (vpath) {
            const int bb = gr0 >> 10;        // batch (256-row tiles never cross)
            const int mb = gr0 & 1023;       // m base within sequence
#pragma unroll
            for (int it = 0; it < 4; ++it) {
                int idx = it * 512 + tid;    // 2048 segs: dc in [0,256), mseg in [0,8)
                int dc = idx >> 3, mseg = idx & 7;
                int hh = (col0 - 2048 + dc) >> 7;
                int dd = (col0 - 2048 + dc) & 127;
                *(short8*)(Vt + ((size_t)(bb * 8 + hh)) * (HDIM * SEQ)
                              + (size_t)dd * SEQ + mb + mseg * 8) =
                    *(const short8*)(&smem.vt[dc * 66 + mseg * 8]);
            }
        } else if (OUT_BF16) {
#pragma unroll
            for (int it = 0; it < 4; ++it) {
                int idx = it * 512 + tid;          // 2048 segs of 8 u16
                int r = idx >> 5, seg = idx & 31;
                *(short8*)((u16*)C + (size_t)(gr0 + r) * N + col0 + seg * 8) =
                    *(const short8*)(&smem.ob[r * 264 + seg * 8]);
            }
        } else {
#pragma unroll
            for (int it = 0; it < 8; ++it) {
                int idx = it * 512 + tid;          // 4096 segs of 4 f32
                int r = idx >> 6, seg = idx & 63;
                *(f32x4*)((float*)C + (size_t)(gr0 + r) * N + col0 + seg * 4) =
                    *(const f32x4*)(&smem.of[r * 268 + seg * 4]);
            }
        }
    }
}

// ---------------- attention: 4 waves x 32 q-rows, swapped-QK, in-register P ---
// R7: O written into the qkv buffer's V-third (cols 2048..3071, stride QSTR) —
// disjoint from the Q/K columns every attn block reads, so race-free; frees
// xb so LN1 can read bf16.  p2frag now permlane-based (see above).
__global__ __launch_bounds__(256, 3) void k_attn(const u16* __restrict__ QKV,
                                                 const u16* __restrict__ Vt,
                                                 u16* __restrict__ O,
                                                 float* __restrict__ csp) {
    union Sm {
        u16 K2[2][8192];                                   // pass A: 64-key dbuf (32KB)
        struct { u16 Kl[2][4096]; u16 Vl[2][4096]; } pb;   // pass B: 32-key dbufs
    };
    __shared__ Sm sm;
    __shared__ float cs[1024];       // column sums (4KB)
    const int id = blockIdx.x;
    const int id2 = (id & 7) * 256 + (id >> 3);   // bijective, 2048 = 8*256
    const int qt = id2 & 7, bh = id2 >> 3;
    const int b = bh >> 3, h = bh & 7;
    const int tid = threadIdx.x, lane = tid & 63, wv = tid >> 6;  // wv in [0,4)
    const int l15 = lane & 15, lg = lane >> 4;

    for (int i = tid; i < 1024; i += 256) cs[i] = 0.f;

    const int q0 = qt * 128 + wv * 32;           // this wave's 32 q-rows
    const u16* qbaseA = QKV + (size_t)(b * SEQ + q0 + l15) * QSTR + h * HDIM + lg * 8;
    const u16* qbaseB = qbaseA + (size_t)16 * QSTR;
    short8 qfA[4], qfB[4];
#pragma unroll
    for (int kk = 0; kk < 4; ++kk) {
        qfA[kk] = *(const short8*)(qbaseA + kk * 32);
        qfB[kk] = *(const short8*)(qbaseB + kk * 32);
    }
    const float CEXP = 0.12751743f;   // (1/sqrt(128)) * log2(e)
    const u16* kbase = QKV + (size_t)(b * SEQ) * QSTR + 1024 + h * HDIM;
    const u16* vtb = Vt + (size_t)bh * HDIM * SEQ;

    // pass A: wave wv stages 4 chunks (its 16 keys, all d) of the 64-key tile
#define STAGE_K2(tt) { _Pragma("unroll")                                        \
    for (int i = 0; i < 4; ++i) {                                               \
        gload_lds16(kbase + (size_t)((tt) * 64 + wv * 16 + l15) * QSTR          \
                    + i * 32 + lg * 8, &sm.K2[(tt) & 1][(wv * 4 + i) * 512]); } }
    // pass B: wave wv stages chunks 2wv, 2wv+1 (of 8) each 32-key tile
#define STAGE_K(tt) { _Pragma("unroll")                                         \
    for (int i = 0; i < 2; ++i) { int c = wv * 2 + i;                           \
        gload_lds16(kbase + (size_t)((tt) * 32 + (c >> 2) * 16 + l15) * QSTR    \
                    + (c & 3) * 32 + lg * 8, &sm.pb.Kl[(tt) & 1][c * 512]); } }
#define STAGE_V(tt) { _Pragma("unroll")                                         \
    for (int i = 0; i < 2; ++i) { int c = wv * 2 + i;                           \
        gload_lds16(vtb + (size_t)(c * 16 + l15) * SEQ + (tt) * 32 + lg * 8,    \
                    &sm.pb.Vl[(tt) & 1][c * 512]); } }

    // ---------------- pass A: per-q rowsums of exp2(s*C), 64-key tiles ---------
    STAGE_K2(0);
    asm volatile("s_waitcnt vmcnt(0)" ::: "memory");
    __builtin_amdgcn_s_barrier();
    f32x4 rsA4 = {0.f, 0.f, 0.f, 0.f}, rsB4 = {0.f, 0.f, 0.f, 0.f};
    for (int t = 0; t < 16; ++t) {
        if (t < 15) STAGE_K2(t + 1);
        const u16* Kp = &sm.K2[t & 1][0];
        __builtin_amdgcn_s_setprio(1);
#pragma unroll
        for (int j = 0; j < 4; j += 2) {
            f32x4 s0 = {0.f,0.f,0.f,0.f}, s1 = {0.f,0.f,0.f,0.f};
            f32x4 s2 = {0.f,0.f,0.f,0.f}, s3 = {0.f,0.f,0.f,0.f};
#pragma unroll
            for (int kk = 0; kk < 4; ++kk) {
                short8 k0 = *(const short8*)(Kp + (j * 4 + kk) * 512 + lane * 8);
                short8 k1 = *(const short8*)(Kp + ((j + 1) * 4 + kk) * 512 + lane * 8);
                s0 = mfma16(k0, qfA[kk], s0);
                s1 = mfma16(k0, qfB[kk], s1);
                s2 = mfma16(k1, qfA[kk], s2);
                s3 = mfma16(k1, qfB[kk], s3);
            }
#pragma unroll
            for (int r = 0; r < 4; ++r) {
                rsA4[r] += __builtin_amdgcn_exp2f(s0[r] * CEXP)
                         + __builtin_amdgcn_exp2f(s2[r] * CEXP);
                rsB4[r] += __builtin_amdgcn_exp2f(s1[r] * CEXP)
                         + __builtin_amdgcn_exp2f(s3[r] * CEXP);
            }
        }
        __builtin_amdgcn_s_setprio(0);
        asm volatile("s_waitcnt vmcnt(0)" ::: "memory");
        __builtin_amdgcn_s_barrier();
    }
    float rsA = (rsA4[0] + rsA4[1]) + (rsA4[2] + rsA4[3]);
    float rsB = (rsB4[0] + rsB4[1]) + (rsB4[2] + rsB4[3]);
    rsA += __shfl_xor(rsA, 16); rsA += __shfl_xor(rsA, 32);
    rsB += __shfl_xor(rsB, 16); rsB += __shfl_xor(rsB, 32);
    // fold normalization into the exponent: exp2(s*C)/rs = exp2(s*C - log2(rs))
    const float lgA = __builtin_amdgcn_logf(rsA);
    const float lgB = __builtin_amdgcn_logf(rsB);

    // ---------------- pass B: P = exp2(sC - log2 rs) ; O += P V ; column sums --
    STAGE_K(0); STAGE_V(0);
    asm volatile("s_waitcnt vmcnt(0)" ::: "memory");
    __builtin_amdgcn_s_barrier();
    f32x4 odA[8] = {}, odB[8] = {};
    for (int t = 0; t < 32; ++t) {
        const int m0 = t * 32;
        if (t < 31) { STAGE_K(t + 1); STAGE_V(t + 1); }
        const u16* Kp = &sm.pb.Kl[t & 1][0];
        f32x4 sA0 = {0.f,0.f,0.f,0.f}, sA1 = {0.f,0.f,0.f,0.f};
        f32x4 sB0 = {0.f,0.f,0.f,0.f}, sB1 = {0.f,0.f,0.f,0.f};
        __builtin_amdgcn_s_setprio(1);
#pragma unroll
        for (int kk = 0; kk < 4; ++kk) {
            short8 k0 = *(const short8*)(Kp + kk * 512 + lane * 8);
            short8 k1 = *(const short8*)(Kp + (4 + kk) * 512 + lane * 8);
            sA0 = mfma16(k0, qfA[kk], sA0);
            sA1 = mfma16(k1, qfA[kk], sA1);
            sB0 = mfma16(k0, qfB[kk], sB0);
            sB1 = mfma16(k1, qfB[kk], sB1);
        }
        __builtin_amdgcn_s_setprio(0);
        f32x4 pA0, pA1, pB0, pB1;
#pragma unroll
        for (int r = 0; r < 4; ++r) {
            pA0[r] = __builtin_amdgcn_exp2f(__builtin_fmaf(sA0[r], CEXP, -lgA));
            pA1[r] = __builtin_amdgcn_exp2f(__builtin_fmaf(sA1[r], CEXP, -lgA));
            pB0[r] = __builtin_amdgcn_exp2f(__builtin_fmaf(sB0[r], CEXP, -lgB));
            pB1[r] = __builtin_amdgcn_exp2f(__builtin_fmaf(sB1[r], CEXP, -lgB));
        }
        // column sums: DPP full-row reduce over the 16 q-lanes
        float csv[8];
#pragma unroll
        for (int r = 0; r < 4; ++r) {
            csv[r]     = pA0[r] + pB0[r];
            csv[4 + r] = pA1[r] + pB1[r];
        }
#pragma unroll
        for (int j2 = 0; j2 < 8; ++j2) {
            DPP_RORADD(csv[j2], 0x128);
            DPP_RORADD(csv[j2], 0x124);
            DPP_RORADD(csv[j2], 0x122);
            DPP_RORADD(csv[j2], 0x121);
        }
        float cval = csv[0];
        cval = (l15 == 1) ? csv[1] : cval;
        cval = (l15 == 2) ? csv[2] : cval;
        cval = (l15 == 3) ? csv[3] : cval;
        cval = (l15 == 4) ? csv[4] : cval;
        cval = (l15 == 5) ? csv[5] : cval;
        cval = (l15 == 6) ? csv[6] : cval;
        cval = (l15 == 7) ? csv[7] : cval;
        if (l15 < 8) {
            int mw = (l15 < 4) ? (lg * 4 + l15) : (16 + lg * 4 + (l15 - 4));
            atomicAdd(&cs[m0 + mw], cval);
        }
        // P -> PV A-fragments, in registers
        short8 paA = p2frag(pA0, pA1, lane);
        short8 paB = p2frag(pB0, pB1, lane);
        const u16* Vb_ = &sm.pb.Vl[t & 1][0];
        __builtin_amdgcn_s_setprio(1);
#pragma unroll
        for (int db = 0; db < 8; ++db) {
            short8 vf = *(const short8*)(Vb_ + db * 512 + lane * 8);
            odA[db] = mfma16(paA, vf, odA[db]);
            odB[db] = mfma16(paB, vf, odB[db]);
        }
        __builtin_amdgcn_s_setprio(0);
        asm volatile("s_waitcnt vmcnt(0)" ::: "memory");
        __builtin_amdgcn_s_barrier();
    }
#undef STAGE_K2
#undef STAGE_K
#undef STAGE_V
    __syncthreads();   // make all waves' cs atomics visible before drain
    // O lives in qkv's V-third: row stride QSTR
    u16* obA = O + (size_t)(b * SEQ + q0 + lg * 4) * QSTR + h * HDIM + l15;
    u16* obB = obA + (size_t)16 * QSTR;
#pragma unroll
    for (int db = 0; db < 8; ++db)
#pragma unroll
        for (int r = 0; r < 4; ++r) {
            obA[(size_t)r * QSTR + db * 16] = f2bf(odA[db][r]);
            obB[(size_t)r * QSTR + db * 16] = f2bf(odB[db][r]);
        }
    for (int m = tid; m < 1024; m += 256)
        csp[((size_t)bh * 8 + qt) * 1024 + m] = cs[m];
}

// ---------------- LN1: LN(x_bf16 + proj_bf16) -> bf16, in-place over x --------
__global__ __launch_bounds__(256) void k_ln1(u16* xio,
                                             const u16* __restrict__ pj,
                                             const float* __restrict__ g,
                                             const float* __restrict__ bt) {
    const int row = blockIdx.x;
    const int t = threadIdx.x, lane = t & 63, wv = t >> 6;
    short4v va = ((const short4v*)(xio + (size_t)row * DIMC))[t];
    short4v hv = ((const short4v*)(pj + (size_t)row * DIMC))[t];
    f32x4 s;
#pragma unroll
    for (int j = 0; j < 4; ++j) s[j] = bf2f((u16)va[j]) + bf2f((u16)hv[j]);
    float sum = s[0] + s[1] + s[2] + s[3];
    float sq = s[0]*s[0] + s[1]*s[1] + s[2]*s[2] + s[3]*s[3];
#pragma unroll
    for (int o = 1; o < 64; o <<= 1) { sum += __shfl_xor(sum, o); sq += __shfl_xor(sq, o); }
    __shared__ float red[8];
    if (lane == 0) { red[wv] = sum; red[4 + wv] = sq; }
    __syncthreads();
    sum = red[0] + red[1] + red[2] + red[3];
    sq  = red[4] + red[5] + red[6] + red[7];
    float mu = sum * (1.f / DIMC);
    float rstd = rsqrtf(sq * (1.f / DIMC) - mu * mu + 1e-5f);
    f32x4 gg = ((const f32x4*)g)[t];
    f32x4 bb = ((const f32x4*)bt)[t];
    uint32_t lo, hi;
    float o0 = (s[0] - mu) * rstd * gg[0] + bb[0];
    float o1 = (s[1] - mu) * rstd * gg[1] + bb[1];
    float o2 = (s[2] - mu) * rstd * gg[2] + bb[2];
    float o3 = (s[3] - mu) * rstd * gg[3] + bb[3];
    lo = f2bf(o0) | ((uint32_t)f2bf(o1) << 16);
    hi = f2bf(o2) | ((uint32_t)f2bf(o3) << 16);
    ((uint2*)(xio + (size_t)row * DIMC))[t] = make_uint2(lo, hi);
}

// ---------------- LN2: LN(h_bf16 + ff2_bf16) -> fp32 out ----------------
__global__ __launch_bounds__(256) void k_ln2(const u16* __restrict__ xa,
                                             const u16* __restrict__ f2,
                                             const float* __restrict__ g,
                                             const float* __restrict__ bt,
                                             float* __restrict__ of) {
    const int row = blockIdx.x;
    const int t = threadIdx.x, lane = t & 63, wv = t >> 6;
    short4v hv = ((const short4v*)(xa + (size_t)row * DIMC))[t];
    short4v fv = ((const short4v*)(f2 + (size_t)row * DIMC))[t];
    f32x4 s;
#pragma unroll
    for (int j = 0; j < 4; ++j) s[j] = bf2f((u16)hv[j]) + bf2f((u16)fv[j]);
    float sum = s[0] + s[1] + s[2] + s[3];
    float sq = s[0]*s[0] + s[1]*s[1] + s[2]*s[2] + s[3]*s[3];
#pragma unroll
    for (int o = 1; o < 64; o <<= 1) { sum += __shfl_xor(sum, o); sq += __shfl_xor(sq, o); }
    __shared__ float red[8];
    if (lane == 0) { red[wv] = sum; red[4 + wv] = sq; }
    __syncthreads();
    sum = red[0] + red[1] + red[2] + red[3];
    sq  = red[4] + red[5] + red[6] + red[7];
    float mu = sum * (1.f / DIMC);
    float rstd = rsqrtf(sq * (1.f / DIMC) - mu * mu + 1e-5f);
    f32x4 gg = ((const f32x4*)g)[t];
    f32x4 bb = ((const f32x4*)bt)[t];
    f32x4 o4;
#pragma unroll
    for (int j = 0; j < 4; ++j) o4[j] = (s[j] - mu) * rstd * gg[j] + bb[j];
    ((f32x4*)(of + (size_t)row * DIMC))[t] = o4;
}

// ---------------- halting: reduce column-sum partials, /H, softmax, add --------
__global__ __launch_bounds__(256) void k_halt(const float* __restrict__ csp,
                                              const float* __restrict__ hs,
                                              float* __restrict__ halt_out,
                                              float* __restrict__ a_out) {
    const int b = blockIdx.x, t = threadIdx.x, lane = t & 63, wv = t >> 6;
    const float* base = csp + (size_t)b * 65536;   // 8 h * 8 qt * 1024
    float acc[4] = {0.f, 0.f, 0.f, 0.f};
    for (int s2 = 0; s2 < 64; ++s2) {
#pragma unroll
        for (int j = 0; j < 4; ++j) acc[j] += base[(size_t)s2 * 1024 + j * 256 + t];
    }
    float mx = -1e30f;
#pragma unroll
    for (int j = 0; j < 4; ++j) { acc[j] *= 0.125f; mx = fmaxf(mx, acc[j]); }
#pragma unroll
    for (int o = 1; o < 64; o <<= 1) mx = fmaxf(mx, __shfl_xor(mx, o));
    __shared__ float red[8];
    if (lane == 0) red[wv] = mx;
    __syncthreads();
    mx = fmaxf(fmaxf(red[0], red[1]), fmaxf(red[2], red[3]));
    float e[4]; float sum = 0.f;
#pragma unroll
    for (int j = 0; j < 4; ++j) { e[j] = __expf(acc[j] - mx); sum += e[j]; }
#pragma unroll
    for (int o = 1; o < 64; o <<= 1) sum += __shfl_xor(sum, o);
    if (lane == 0) red[4 + wv] = sum;
    __syncthreads();
    sum = red[4] + red[5] + red[6] + red[7];
    float inv = 1.f / sum;
#pragma unroll
    for (int j = 0; j < 4; ++j) {
        int m = j * 256 + t;
        float a = e[j] * inv;
        a_out[b * SEQ + m] = a;
        halt_out[b * SEQ + m] = hs[b * SEQ + m] + a;
    }
}

// =======================================================================
// workspace layout (<= 352 MiB):
//   [0,64)    xb (bf16 x; survives) -> hb via in-place LN1
//   [64,256)  qkv bf16; V-third (cols 2048..3071) doubles as attn-O (o_b).
//             Q+K thirds dead after attn -> ff1 [64,192), ff2b [192,224)
//   [256,320) Vt (QKV epilogue; dead after attn) -> projb
//   [320,344) transposed bf16 weights (WqkvT 6MB | WpT 2MB | W1T 8MB | W2T 8MB)
//   [344,352) colsum partials
// =======================================================================
extern "C" void kernel_launch(void* const* d_in, const int* in_sizes, int n_in,
                              void* d_out, int out_size, void* d_ws, size_t ws_size,
                              hipStream_t stream) {
    (void)in_sizes; (void)n_in; (void)out_size; (void)ws_size;
    const float* x   = (const float*)d_in[0];
    const float* hs  = (const float*)d_in[1];
    const float* Wq  = (const float*)d_in[2];
    const float* Wkv = (const float*)d_in[3];
    const float* Wp  = (const float*)d_in[4];
    const float* bp  = (const float*)d_in[5];
    const float* W1  = (const float*)d_in[6];
    const float* b1  = (const float*)d_in[7];
    const float* W2  = (const float*)d_in[8];
    const float* b2  = (const float*)d_in[9];
    const float* g1  = (const float*)d_in[10];
    const float* be1 = (const float*)d_in[11];
    const float* g2  = (const float*)d_in[12];
    const float* be2 = (const float*)d_in[13];

    float* out = (float*)d_out;
    float* halt_out = out + (size_t)SROWS * DIMC;
    float* a_out = halt_out + SROWS;

    char* w = (char*)d_ws;
    const size_t MB = 1024 * 1024;
    u16*  xb    = (u16*)(w);                // bf16 x, survives until LN1 (in-place -> hb)
    u16*  qkv   = (u16*)(w + 64 * MB);
    u16*  Vt    = (u16*)(w + 256 * MB);
    u16*  WqkvT = (u16*)(w + 320 * MB);
    u16*  WpT   = (u16*)(w + 326 * MB);
    u16*  W1T   = (u16*)(w + 328 * MB);
    u16*  W2T   = (u16*)(w + 336 * MB);
    float* csp  = (float*)(w + 344 * MB);
    u16*  o_b   = qkv + 2048;               // attn O in qkv V-third, stride QSTR
    u16*  projb = (u16*)(w + 256 * MB);     // over Vt (dead after attn)
    u16*  hb    = xb;                       // LN1 in-place
    u16*  ff1   = (u16*)(w + 64 * MB);      // over qkv Q+K thirds (dead after attn)
    u16*  ff2b  = (u16*)(w + 192 * MB);     // over qkv tail

    dim3 tb(32, 8);
    // casts + weight transposes (Wq and Wkv land in one contiguous WqkvT)
    k_cast<<<SROWS * DIMC / 4 / 256, 256, 0, stream>>>(x, xb, SROWS * DIMC / 4);
    k_transpose_cast<<<dim3(DIMC / 32, DIMC / 32), tb, 0, stream>>>(Wq, WqkvT, DIMC, DIMC);
    k_transpose_cast<<<dim3(2 * DIMC / 32, DIMC / 32), tb, 0, stream>>>(
        Wkv, WqkvT + (size_t)DIMC * DIMC, DIMC, 2 * DIMC);
    k_transpose_cast<<<dim3(DIMC / 32, DIMC / 32), tb, 0, stream>>>(Wp, WpT, DIMC, DIMC);
    k_transpose_cast<<<dim3(FFND / 32, DIMC / 32), tb, 0, stream>>>(W1, W1T, DIMC, FFND);
    k_transpose_cast<<<dim3(DIMC / 32, FFND / 32), tb, 0, stream>>>(W2, W2T, FFND, DIMC);
    // fused QKV gemm (N = 3072); V columns written transposed into Vt
    k_gemm256<true, false, false, true><<<dim3(QSTR / 256, SROWS / 256), 512, 0, stream>>>(
        xb, WqkvT, nullptr, qkv, Vt, SROWS, QSTR, DIMC, DIMC);
    // attention (256 threads: 4 waves x 32 q-rows); O -> qkv V-third
    k_attn<<<2048, 256, 0, stream>>>(qkv, Vt, o_b, csp);
    // output projection (+bp) -> bf16 projb (A = o_b with lda = QSTR)
    k_gemm256<true, false, true, false><<<dim3(DIMC / 256, SROWS / 256), 512, 0, stream>>>(
        o_b, WpT, bp, projb, nullptr, SROWS, DIMC, DIMC, QSTR);
    // LN1: h = LN(xb + proj) -> bf16, in-place over xb
    k_ln1<<<SROWS, 256, 0, stream>>>(xb, projb, g1, be1);
    // FFN in 2 row chunks of 16384
    for (int c = 0; c < 2; ++c) {
        const size_t ro = (size_t)c * 16384;
        k_gemm256<true, true, true, false><<<dim3(FFND / 256, 16384 / 256), 512, 0, stream>>>(
            hb + ro * DIMC, W1T, b1, ff1, nullptr, 16384, FFND, DIMC, DIMC);
        k_gemm256<true, false, true, false><<<dim3(DIMC / 256, 16384 / 256), 512, 0, stream>>>(
            ff1, W2T, b2, ff2b, nullptr, 16384, DIMC, FFND, FFND);
        k_ln2<<<16384, 256, 0, stream>>>(hb + ro * DIMC, ff2b, g2, be2, out + ro * DIMC);
    }
    // halting score
    k_halt<<<BATCH, 256, 0, stream>>>(csp, hs, halt_out, a_out);
}